// Round 17
// baseline (196.517 us; speedup 1.0000x reference)
//
#include <hip/hip_runtime.h>
#include <stdint.h>

typedef __bf16 bf16;
typedef __bf16 bf16x2 __attribute__((ext_vector_type(2)));
typedef __bf16 bf16x4 __attribute__((ext_vector_type(4)));
typedef __bf16 bf16x8 __attribute__((ext_vector_type(8)));
typedef float f32x4 __attribute__((ext_vector_type(4)));
typedef unsigned u32x2 __attribute__((ext_vector_type(2)));

// XOR swizzle for [rows][32] bf16 LDS tiles (64B row stride).
__device__ __forceinline__ int swz(int row, int colb) {
    return (row * 64 + colb) ^ ((row & 7) << 4);
}

__device__ __forceinline__ unsigned packb(float a, float b) {
    bf16x2 t; t[0] = (bf16)a; t[1] = (bf16)b;
    return __builtin_bit_cast(unsigned, t);
}

// async global->LDS 16B copy (dest = wave-uniform base + lane*16)
__device__ __forceinline__ void gload16(void* lds, const void* g) {
    __builtin_amdgcn_global_load_lds(
        (const __attribute__((address_space(1))) void*)g,
        (__attribute__((address_space(3))) void*)lds, 16, 0, 0);
}

// ---------------- prep: q/k/v cvt + weight transpose + mask pack (one launch) --
__global__ __launch_bounds__(256) void prep_kernel(
    const float* __restrict__ q, const float* __restrict__ k, const float* __restrict__ v,
    bf16* __restrict__ oq, bf16* __restrict__ ok, bf16* __restrict__ ov,
    const float* __restrict__ w0, const float* __restrict__ w1,
    const float* __restrict__ w2, const float* __restrict__ w3,
    bf16* __restrict__ t0, bf16* __restrict__ t1,
    bf16* __restrict__ t2, bf16* __restrict__ t3,
    const int* __restrict__ mask, unsigned long long* __restrict__ mbits)
{
    int bid = blockIdx.x;
    int tid = threadIdx.x;
    __shared__ float tile[32][33];

    if (bid < 6144) {
        int z = bid >> 11;
        int bx = bid & 2047;
        const float* src = z == 0 ? q : z == 1 ? k : v;
        bf16* dst = z == 0 ? oq : z == 1 ? ok : ov;
        size_t i = ((size_t)bx * 256 + tid) * 8;
        f32x4 a = *(const f32x4*)(src + i);
        f32x4 b = *(const f32x4*)(src + i + 4);
        bf16x8 o;
#pragma unroll
        for (int j = 0; j < 4; ++j) { o[j] = (bf16)a[j]; o[4 + j] = (bf16)b[j]; }
        *(bf16x8*)(dst + i) = o;
    } else if (bid < 10240) {
        int wid = bid - 6144;
        int z = wid >> 10;
        int t = wid & 1023;
        const float* W = z == 0 ? w0 : z == 1 ? w1 : z == 2 ? w2 : w3;
        bf16* O = z == 0 ? t0 : z == 1 ? t1 : z == 2 ? t2 : t3;
        int c0 = (t & 31) * 32, r0 = (t >> 5) * 32;
        int tx = tid & 31, ty = tid >> 5; // (32,8)
#pragma unroll
        for (int i = 0; i < 4; ++i)
            tile[ty + i * 8][tx] = W[(size_t)(r0 + ty + i * 8) * 1024 + c0 + tx];
        __syncthreads();
#pragma unroll
        for (int i = 0; i < 4; ++i)
            O[(size_t)(c0 + ty + i * 8) * 1024 + r0 + tx] = (bf16)tile[tx][ty + i * 8];
    } else {
        int mb = bid - 10240;
        int lane = tid & 63;
        int wid = (mb * 256 + tid) >> 6;
        int nw = (256 * 256) >> 6;
        const int niter = (4 * 1024 * 1024) / 64;
        for (int i = wid; i < niter; i += nw) {
            int vv = mask[(size_t)i * 64 + lane];
            unsigned long long bb = __ballot(vv != 0);
            if (lane == 0) mbits[i] = bb;
        }
    }
}

// ---------------- projection GEMM (gload_lds staging) ----------------
// z==0/1: head-major Q/K. z==2: writes V^T (B,H,64,S) directly.
__global__ __launch_bounds__(256) void proj_gemm(
    const bf16* __restrict__ Aq, const bf16* __restrict__ Ak, const bf16* __restrict__ Av,
    const bf16* __restrict__ Wq, const bf16* __restrict__ Wk, const bf16* __restrict__ Wv,
    bf16* __restrict__ Oq, bf16* __restrict__ Ok, bf16* __restrict__ OvT)
{
    int z = blockIdx.z;
    const bf16* A = z == 0 ? Aq : z == 1 ? Ak : Av;
    const bf16* WT = z == 0 ? Wq : z == 1 ? Wk : Wv;

    __shared__ bf16 Al[128 * 32];
    __shared__ bf16 Bl[128 * 32];

    int tid = threadIdx.x;
    int w = tid >> 6, l = tid & 63;
    int l15 = l & 15, lg = l >> 4;
    int m0 = blockIdx.y * 128, n0 = blockIdx.x * 128;
    int wm = (w >> 1) * 64, wn = (w & 1) * 64;

    int rr0 = tid >> 2;
    int row0 = rr0 ^ ((rr0 >> 2) & 1);
    int cbe = (((tid & 3) * 16) ^ ((row0 & 3) << 4)) >> 1;
    char* aldst0 = (char*)Al + w * 1024;
    char* aldst1 = (char*)Al + 4096 + w * 1024;
    char* bldst0 = (char*)Bl + w * 1024;
    char* bldst1 = (char*)Bl + 4096 + w * 1024;
    const bf16* asrc0 = A + (size_t)(m0 + row0) * 1024 + cbe;
    const bf16* asrc1 = A + (size_t)(m0 + row0 + 64) * 1024 + cbe;
    const bf16* bsrc0 = WT + (size_t)(n0 + row0) * 1024 + cbe;
    const bf16* bsrc1 = WT + (size_t)(n0 + row0 + 64) * 1024 + cbe;

    const f32x4 fz = {0.f, 0.f, 0.f, 0.f};
    f32x4 acc[4][4];
#pragma unroll
    for (int i = 0; i < 4; ++i)
#pragma unroll
        for (int j = 0; j < 4; ++j) acc[i][j] = fz;

    for (int k0 = 0; k0 < 1024; k0 += 32) {
        gload16(aldst0, asrc0 + k0);
        gload16(aldst1, asrc1 + k0);
        gload16(bldst0, bsrc0 + k0);
        gload16(bldst1, bsrc1 + k0);
        __syncthreads();
        bf16x8 af[4], bv[4];
#pragma unroll
        for (int i = 0; i < 4; ++i)
            af[i] = *(const bf16x8*)((const char*)Al + swz(wm + i * 16 + l15, lg * 16));
#pragma unroll
        for (int j = 0; j < 4; ++j)
            bv[j] = *(const bf16x8*)((const char*)Bl + swz(wn + j * 16 + l15, lg * 16));
#pragma unroll
        for (int i = 0; i < 4; ++i)
#pragma unroll
            for (int j = 0; j < 4; ++j)
                acc[i][j] = __builtin_amdgcn_mfma_f32_16x16x32_bf16(af[i], bv[j], acc[i][j], 0, 0, 0);
        __syncthreads();
    }
    if (z < 2) {
        bf16* O = z == 0 ? Oq : Ok;
#pragma unroll
        for (int i = 0; i < 4; ++i)
#pragma unroll
            for (int j = 0; j < 4; ++j)
#pragma unroll
                for (int r = 0; r < 4; ++r) {
                    int m = m0 + wm + i * 16 + lg * 4 + r;
                    int n = n0 + wn + j * 16 + l15;
                    int bb = m >> 10, s = m & 1023, h = n >> 6, d = n & 63;
                    O[((size_t)(bb * 16 + h) * 1024 + s) * 64 + d] = (bf16)acc[i][j][r];
                }
    } else {
#pragma unroll
        for (int i = 0; i < 4; ++i)
#pragma unroll
            for (int j = 0; j < 4; ++j) {
                int m = m0 + wm + i * 16 + lg * 4;
                int n = n0 + wn + j * 16 + l15;
                int bb = m >> 10, s = m & 1023, h = n >> 6, d = n & 63;
                bf16x4 cv;
#pragma unroll
                for (int r = 0; r < 4; ++r) cv[r] = (bf16)acc[i][j][r];
                *(bf16x4*)(OvT + ((size_t)(bb * 16 + h) * 64 + d) * 1024 + s) = cv;
            }
    }
}

// ---------------- fused attention (R13) + global_load_lds K/V staging ---------
// Phase 1: K/V DOUBLE-buffered (16+16KB) staged via async global_load_lds with
// inverse-swizzled per-lane sources (rule #21: linear dest, same LDS bytes as
// before) -> no ds_write staging ops, 1 barrier/chunk. St 8KB. 40KB = 4 blk/CU.
// Phase 2: same treatment for dbuf K. sinv aliased onto dead St region.
__global__ __launch_bounds__(256, 4) void attn_fused(
    const bf16* __restrict__ Qh, const bf16* __restrict__ Kh,
    const bf16* __restrict__ VhT, const unsigned* __restrict__ mbits,
    bf16* __restrict__ ctx, float* __restrict__ attn_out)
{
    int bh = blockIdx.x;
    int b = bh >> 4, h = bh & 15;
    int tid = threadIdx.x;
    int w = tid >> 6, l = tid & 63;
    int l15 = l & 15, lg = l >> 4;
    int q0 = blockIdx.y * 64 + w * 16;

    const bf16* Qb = Qh + (size_t)bh * 65536;
    const bf16* Kb = Kh + (size_t)bh * 65536;
    const bf16* Vt = VhT + (size_t)bh * 65536;
    const unsigned* mbrow = mbits + ((size_t)b * 1024 + q0 + l15) * 32;

    __shared__ char lds[40960];
    // phase 1: K dbuf [0,16384), V dbuf [16384,32768), St [32768,40960)
    char* const St = lds + 32768 + w * 2048;   // wave-private [16 q][128B keys]
    float* const sinv = (float*)(lds + 32768); // aliased after St is dead
    // phase 2: K0=[0,8192) K1=[8192,16384) S2 in V region
    char* const S2 = lds + 16384 + w * 2560;   // 16 rows x 160B, wave-private

    const int rsw = (l15 & 7) << 4;
    const int ko0 = (lg * 16) ^ rsw;
    const int ko1 = (64 + lg * 16) ^ rsw;

    // gload staging coords: wave w covers dest [w*2KB, w*2KB+2KB) of each 8KB
    // tile (2 issues). Inverse-swizzled per-lane source (content identical to
    // the old ds_write layout).
    const int oA = (w * 2) * 1024 + l * 16;
    const int oB = oA + 1024;
    const int rA = oA >> 7, cA = oA & 127;
    const int rB = oB >> 7, cB = oB & 127;
    const int sAo = rA * 128 + (cA ^ ((rA & 7) << 4));   // K src byte off in 8KB chunk
    const int sBo = rB * 128 + (cB ^ ((rB & 7) << 4));
    const int vAo = rA * 2048 + (cA ^ ((rA & 7) << 4));  // V src: row rA, 128B per chunk
    const int vBo = rB * 2048 + (cB ^ ((rB & 7) << 4));
    const char* KbS = (const char*)Kb;
    const char* VtS = (const char*)Vt;
    char* const kd = lds + (w * 2) * 1024;               // dest bases (wave-uniform)
    char* const vd = lds + 16384 + (w * 2) * 1024;

    bf16x8 qf0 = *(const bf16x8*)(Qb + (size_t)(q0 + l15) * 64 + lg * 8);
    bf16x8 qf1 = *(const bf16x8*)(Qb + (size_t)(q0 + l15) * 64 + 32 + lg * 8);

    const f32x4 fz = {0.f, 0.f, 0.f, 0.f};

    // ================= phase 1 =================
    // prologue: stage chunk 0 into buffer 0
    gload16(kd,        KbS + sAo);
    gload16(kd + 1024, KbS + sBo);
    gload16(vd,        VtS + vAo);
    gload16(vd + 1024, VtS + vBo);
    __syncthreads();

    f32x4 oacc[4];
#pragma unroll
    for (int d0 = 0; d0 < 4; ++d0) oacc[d0] = fz;
    float ps = 0.f;

    for (int c = 0; c < 16; ++c) {
        if (c < 15) {   // async-stage chunk c+1 into the other buffer
            int nb = (c + 1) & 1;
            gload16(kd + nb * 8192,        KbS + (c + 1) * 8192 + sAo);
            gload16(kd + nb * 8192 + 1024, KbS + (c + 1) * 8192 + sBo);
            gload16(vd + nb * 8192,        VtS + (c + 1) * 128 + vAo);
            gload16(vd + nb * 8192 + 1024, VtS + (c + 1) * 128 + vBo);
        }
        const char* Kc = lds + (c & 1) * 8192;
        const char* Vc = lds + 16384 + (c & 1) * 8192;
        u32x2 mw = *(const u32x2*)(mbrow + c * 2);
        f32x4 st[4];
#pragma unroll
        for (int f = 0; f < 4; ++f) st[f] = fz;
#pragma unroll
        for (int f = 0; f < 4; ++f) {
            bf16x8 kf = *(const bf16x8*)(Kc + (f * 16 + l15) * 128 + ko0);
            st[f] = __builtin_amdgcn_mfma_f32_16x16x32_bf16(kf, qf0, st[f], 0, 0, 0);
        }
#pragma unroll
        for (int f = 0; f < 4; ++f) {
            bf16x8 kf = *(const bf16x8*)(Kc + (f * 16 + l15) * 128 + ko1);
            st[f] = __builtin_amdgcn_mfma_f32_16x16x32_bf16(kf, qf1, st[f], 0, 0, 0);
        }
        // masked exp; write P row-major into wave-private St
#pragma unroll
        for (int f = 0; f < 4; ++f) {
            unsigned wb = mw[f >> 1] >> (((f & 1) << 4) + (lg << 2));
            f32x4 o;
            o[0] = (wb & 1u)        ? __expf(st[f][0] * 0.125f) : 0.f;
            o[1] = ((wb >> 1) & 1u) ? __expf(st[f][1] * 0.125f) : 0.f;
            o[2] = ((wb >> 2) & 1u) ? __expf(st[f][2] * 0.125f) : 0.f;
            o[3] = ((wb >> 3) & 1u) ? __expf(st[f][3] * 0.125f) : 0.f;
            ps += (o[0] + o[1]) + (o[2] + o[3]);
            u32x2 pr; pr[0] = packb(o[0], o[1]); pr[1] = packb(o[2], o[3]);
            *(u32x2*)(St + l15 * 128 + ((f * 32 + lg * 8) ^ rsw)) = pr;
        }
        // PV: B-frag = contiguous read of St row q=l15
#pragma unroll
        for (int ks = 0; ks < 2; ++ks) {
            bf16x8 pf = *(const bf16x8*)(St + l15 * 128 + ((ks * 64 + lg * 16) ^ rsw));
#pragma unroll
            for (int d0 = 0; d0 < 4; ++d0) {
                bf16x8 vf = *(const bf16x8*)(Vc + (d0 * 16 + l15) * 128 + ((ks * 64 + lg * 16) ^ rsw));
                oacc[d0] = __builtin_amdgcn_mfma_f32_16x16x32_bf16(vf, pf, oacc[d0], 0, 0, 0);
            }
        }
        __syncthreads();   // readers done with buf c; buf c+1 landed (vmcnt drain)
    }
    ps += __shfl_xor(ps, 16, 64);
    ps += __shfl_xor(ps, 32, 64);
    float inv = 1.f / ps;

    bf16* crow = ctx + ((size_t)(b * 1024 + q0 + l15)) * 1024 + h * 64;
#pragma unroll
    for (int d0 = 0; d0 < 4; ++d0) {
        bf16x4 cv;
#pragma unroll
        for (int r = 0; r < 4; ++r) cv[r] = (bf16)(oacc[d0][r] * inv);
        *(bf16x4*)(crow + d0 * 16 + lg * 4) = cv;
    }
    __syncthreads();   // all St reads done -> safe to alias sinv onto St region
    if (l < 16) sinv[w * 16 + l15] = inv;
    __syncthreads();   // sinv visible to all waves

    // ================= phase 2 =================
    const int rq = l >> 3;               // 0..7
    const int rk = (l & 7) * 4;          // 0..28
    const float iv0 = sinv[w * 16 + rq];
    const float iv1 = sinv[w * 16 + 8 + rq];
    const unsigned* mb0 = mbits + ((size_t)b * 1024 + q0 + rq) * 32;
    const unsigned* mb1 = mbits + ((size_t)b * 1024 + q0 + 8 + rq) * 32;
    float* abase = attn_out + ((size_t)bh * 1024 + q0) * 1024;

    // prologue: stage chunk 0 K into K0 (L2-hot from phase 1)
    gload16(kd,        KbS + sAo);
    gload16(kd + 1024, KbS + sBo);

    for (int c = 0; c < 16; ++c) {
        __syncthreads();   // staged chunk c landed; prev readers done
        if (c < 15) {
            int nb = (c + 1) & 1;
            gload16(kd + nb * 8192,        KbS + (c + 1) * 8192 + sAo);
            gload16(kd + nb * 8192 + 1024, KbS + (c + 1) * 8192 + sBo);
        }
        u32x2 mw0 = *(const u32x2*)(mb0 + c * 2);
        u32x2 mw1 = *(const u32x2*)(mb1 + c * 2);
        const char* Kc = lds + (c & 1) * 8192;
        f32x4 st[4];
#pragma unroll
        for (int f = 0; f < 4; ++f) st[f] = fz;
#pragma unroll
        for (int f = 0; f < 4; ++f) {
            bf16x8 kf = *(const bf16x8*)(Kc + (f * 16 + l15) * 128 + ko0);
            st[f] = __builtin_amdgcn_mfma_f32_16x16x32_bf16(kf, qf0, st[f], 0, 0, 0);
        }
#pragma unroll
        for (int f = 0; f < 4; ++f) {
            bf16x8 kf = *(const bf16x8*)(Kc + (f * 16 + l15) * 128 + ko1);
            st[f] = __builtin_amdgcn_mfma_f32_16x16x32_bf16(kf, qf1, st[f], 0, 0, 0);
        }
        const int qsw = (l15 & 7) << 3;
#pragma unroll
        for (int f = 0; f < 4; ++f) {
#pragma unroll
            for (int j = 0; j < 2; ++j) {
                unsigned val = packb(__expf(st[f][2 * j] * 0.125f),
                                     __expf(st[f][2 * j + 1] * 0.125f));
                int kbyte = f * 32 + lg * 8 + j * 4;
                *(unsigned*)(S2 + l15 * 160 + (kbyte ^ qsw)) = val;
            }
        }
#pragma unroll
        for (int ri = 0; ri < 4; ++ri) {
            int qq = rq + 8 * (ri & 1);
            int kk = rk + 32 * (ri >> 1);
            bf16x4 pv4 = *(const bf16x4*)(S2 + qq * 160 + ((kk * 2) ^ ((qq & 7) << 3)));
            unsigned wm = ((ri & 1) ? mw1[ri >> 1] : mw0[ri >> 1]) >> rk;
            float iv = (ri & 1) ? iv1 : iv0;
            f32x4 o;
            o[0] = (wm & 1u)        ? (float)pv4[0] * iv : 0.f;
            o[1] = ((wm >> 1) & 1u) ? (float)pv4[1] * iv : 0.f;
            o[2] = ((wm >> 2) & 1u) ? (float)pv4[2] * iv : 0.f;
            o[3] = ((wm >> 3) & 1u) ? (float)pv4[3] * iv : 0.f;
            // nontemporal: attn is write-once streaming output
            __builtin_nontemporal_store(o, (f32x4*)(abase + (size_t)qq * 1024 + c * 64 + kk));
        }
    }
}

// ---------------- FC GEMM + residual -> preLN f32 ----------------
__global__ __launch_bounds__(256) void fc_gemm(
    const bf16* __restrict__ ctx, const bf16* __restrict__ WT,
    const float* __restrict__ resid, float* __restrict__ preLN)
{
    __shared__ bf16 Al[128 * 32];
    __shared__ bf16 Bl[128 * 32];
    int tid = threadIdx.x;
    int w = tid >> 6, l = tid & 63;
    int l15 = l & 15, lg = l >> 4;
    int m0 = blockIdx.y * 128, n0 = blockIdx.x * 128;
    int wm = (w >> 1) * 64, wn = (w & 1) * 64;

    int rr0 = tid >> 2;
    int row0 = rr0 ^ ((rr0 >> 2) & 1);
    int cbe = (((tid & 3) * 16) ^ ((row0 & 3) << 4)) >> 1;
    char* aldst0 = (char*)Al + w * 1024;
    char* aldst1 = (char*)Al + 4096 + w * 1024;
    char* bldst0 = (char*)Bl + w * 1024;
    char* bldst1 = (char*)Bl + 4096 + w * 1024;
    const bf16* asrc0 = ctx + (size_t)(m0 + row0) * 1024 + cbe;
    const bf16* asrc1 = ctx + (size_t)(m0 + row0 + 64) * 1024 + cbe;
    const bf16* bsrc0 = WT + (size_t)(n0 + row0) * 1024 + cbe;
    const bf16* bsrc1 = WT + (size_t)(n0 + row0 + 64) * 1024 + cbe;

    const f32x4 fz = {0.f, 0.f, 0.f, 0.f};
    f32x4 acc[4][4];
#pragma unroll
    for (int i = 0; i < 4; ++i)
#pragma unroll
        for (int j = 0; j < 4; ++j) acc[i][j] = fz;

    for (int k0 = 0; k0 < 1024; k0 += 32) {
        gload16(aldst0, asrc0 + k0);
        gload16(aldst1, asrc1 + k0);
        gload16(bldst0, bsrc0 + k0);
        gload16(bldst1, bsrc1 + k0);
        __syncthreads();
        bf16x8 af[4], bv[4];
#pragma unroll
        for (int i = 0; i < 4; ++i)
            af[i] = *(const bf16x8*)((const char*)Al + swz(wm + i * 16 + l15, lg * 16));
#pragma unroll
        for (int j = 0; j < 4; ++j)
            bv[j] = *(const bf16x8*)((const char*)Bl + swz(wn + j * 16 + l15, lg * 16));
#pragma unroll
        for (int i = 0; i < 4; ++i)
#pragma unroll
            for (int j = 0; j < 4; ++j)
                acc[i][j] = __builtin_amdgcn_mfma_f32_16x16x32_bf16(af[i], bv[j], acc[i][j], 0, 0, 0);
        __syncthreads();
    }
#pragma unroll
    for (int i = 0; i < 4; ++i)
#pragma unroll
        for (int j = 0; j < 4; ++j)
#pragma unroll
            for (int r = 0; r < 4; ++r) {
                int m = m0 + wm + i * 16 + lg * 4 + r;
                int n = n0 + wn + j * 16 + l15;
                preLN[(size_t)m * 1024 + n] = acc[i][j][r] + resid[(size_t)m * 1024 + n];
            }
}

// ---------------- LayerNorm ----------------
__global__ __launch_bounds__(256) void ln_kernel(
    const float* __restrict__ x, const float* __restrict__ gamma,
    const float* __restrict__ beta, float* __restrict__ out)
{
    int row = blockIdx.x, t = threadIdx.x;
    const float* xr = x + (size_t)row * 1024;
    f32x4 v = *(const f32x4*)(xr + t * 4);
    float s = v[0] + v[1] + v[2] + v[3];
    float s2 = v[0] * v[0] + v[1] * v[1] + v[2] * v[2] + v[3] * v[3];
#pragma unroll
    for (int m = 1; m < 64; m <<= 1) {
        s += __shfl_xor(s, m, 64);
        s2 += __shfl_xor(s2, m, 64);
    }
    __shared__ float rs[4], rs2[4];
    if ((t & 63) == 0) { rs[t >> 6] = s; rs2[t >> 6] = s2; }
    __syncthreads();
    float S = rs[0] + rs[1] + rs[2] + rs[3];
    float S2 = rs2[0] + rs2[1] + rs2[2] + rs2[3];
    float mu = S * (1.f / 1024.f);
    float var = S2 * (1.f / 1024.f) - mu * mu;
    float rinv = rsqrtf(var + 1e-6f);
    f32x4 g = *(const f32x4*)(gamma + t * 4);
    f32x4 bb = *(const f32x4*)(beta + t * 4);
    f32x4 o;
#pragma unroll
    for (int j = 0; j < 4; ++j) o[j] = (v[j] - mu) * rinv * g[j] + bb[j];
    // out is a write-once streaming output (never re-read on device)
    __builtin_nontemporal_store(o, (f32x4*)(out + (size_t)row * 1024 + t * 4));
}

extern "C" void kernel_launch(void* const* d_in, const int* in_sizes, int n_in,
                              void* d_out, int out_size, void* d_ws, size_t ws_size,
                              hipStream_t stream) {
    const float* q     = (const float*)d_in[0];
    const float* k     = (const float*)d_in[1];
    const float* v     = (const float*)d_in[2];
    const int*   mask  = (const int*)d_in[3];
    const float* w_qs  = (const float*)d_in[4];
    const float* w_ks  = (const float*)d_in[5];
    const float* w_vs  = (const float*)d_in[6];
    const float* w_fc  = (const float*)d_in[7];
    const float* gamma = (const float*)d_in[8];
    const float* beta  = (const float*)d_in[9];

    float* out  = (float*)d_out;
    float* attn = out + (size_t)4 * 1024 * 1024; // second tuple output

    char* ws = (char*)d_ws;
    bf16* wqT   = (bf16*)(ws + (0ull  << 20));
    bf16* wkT   = (bf16*)(ws + (2ull  << 20));
    bf16* wvT   = (bf16*)(ws + (4ull  << 20));
    bf16* wfcT  = (bf16*)(ws + (6ull  << 20));
    bf16* Qh    = (bf16*)(ws + (8ull  << 20));
    bf16* Kh    = (bf16*)(ws + (16ull << 20));
    bf16* VhT   = (bf16*)(ws + (32ull << 20));
    bf16* ctx   = (bf16*)(ws + (40ull << 20));
    float* preLN = (float*)(ws + (48ull << 20));
    unsigned long long* mbits = (unsigned long long*)(ws + (25ull << 20)); // 512KB

    // bf16 copies of q/k/v live in the attn output region (dead until
    // attn_fused phase 2 overwrites every byte; proj reads them first).
    char* scratch = (char*)attn;
    bf16* qb = (bf16*)scratch;
    bf16* kb = qb + (size_t)4 * 1024 * 1024;
    bf16* vb = kb + (size_t)4 * 1024 * 1024;

    prep_kernel<<<10496, 256, 0, stream>>>(q, k, v, qb, kb, vb,
                                           w_qs, w_ks, w_vs, w_fc,
                                           wqT, wkT, wvT, wfcT,
                                           mask, mbits);
    proj_gemm<<<dim3(8, 32, 3), 256, 0, stream>>>(qb, kb, vb, wqT, wkT, wvT,
                                                  Qh, Kh, VhT);
    attn_fused<<<dim3(64, 16), 256, 0, stream>>>(Qh, Kh, VhT, (const unsigned*)mbits,
                                                 ctx, attn);
    fc_gemm<<<dim3(8, 32), 256, 0, stream>>>(ctx, wfcT, q, preLN);
    ln_kernel<<<4096, 256, 0, stream>>>(preLN, gamma, beta, out);
}

// Round 18
// 194.922 us; speedup vs baseline: 1.0082x; 1.0082x over previous
//
#include <hip/hip_runtime.h>
#include <stdint.h>

typedef __bf16 bf16;
typedef __bf16 bf16x2 __attribute__((ext_vector_type(2)));
typedef __bf16 bf16x4 __attribute__((ext_vector_type(4)));
typedef __bf16 bf16x8 __attribute__((ext_vector_type(8)));
typedef float f32x4 __attribute__((ext_vector_type(4)));
typedef unsigned u32x2 __attribute__((ext_vector_type(2)));

// XOR swizzle for [rows][32] bf16 LDS tiles (64B row stride).
__device__ __forceinline__ int swz(int row, int colb) {
    return (row * 64 + colb) ^ ((row & 7) << 4);
}

__device__ __forceinline__ unsigned packb(float a, float b) {
    bf16x2 t; t[0] = (bf16)a; t[1] = (bf16)b;
    return __builtin_bit_cast(unsigned, t);
}

// async global->LDS 16B copy (dest = wave-uniform base + lane*16)
__device__ __forceinline__ void gload16(void* lds, const void* g) {
    __builtin_amdgcn_global_load_lds(
        (const __attribute__((address_space(1))) void*)g,
        (__attribute__((address_space(3))) void*)lds, 16, 0, 0);
}

// ---------------- prep: q/k/v cvt + weight transpose + mask pack (one launch) --
__global__ __launch_bounds__(256) void prep_kernel(
    const float* __restrict__ q, const float* __restrict__ k, const float* __restrict__ v,
    bf16* __restrict__ oq, bf16* __restrict__ ok, bf16* __restrict__ ov,
    const float* __restrict__ w0, const float* __restrict__ w1,
    const float* __restrict__ w2, const float* __restrict__ w3,
    bf16* __restrict__ t0, bf16* __restrict__ t1,
    bf16* __restrict__ t2, bf16* __restrict__ t3,
    const int* __restrict__ mask, unsigned long long* __restrict__ mbits)
{
    int bid = blockIdx.x;
    int tid = threadIdx.x;
    __shared__ float tile[32][33];

    if (bid < 6144) {
        int z = bid >> 11;
        int bx = bid & 2047;
        const float* src = z == 0 ? q : z == 1 ? k : v;
        bf16* dst = z == 0 ? oq : z == 1 ? ok : ov;
        size_t i = ((size_t)bx * 256 + tid) * 8;
        f32x4 a = *(const f32x4*)(src + i);
        f32x4 b = *(const f32x4*)(src + i + 4);
        bf16x8 o;
#pragma unroll
        for (int j = 0; j < 4; ++j) { o[j] = (bf16)a[j]; o[4 + j] = (bf16)b[j]; }
        *(bf16x8*)(dst + i) = o;
    } else if (bid < 10240) {
        int wid = bid - 6144;
        int z = wid >> 10;
        int t = wid & 1023;
        const float* W = z == 0 ? w0 : z == 1 ? w1 : z == 2 ? w2 : w3;
        bf16* O = z == 0 ? t0 : z == 1 ? t1 : z == 2 ? t2 : t3;
        int c0 = (t & 31) * 32, r0 = (t >> 5) * 32;
        int tx = tid & 31, ty = tid >> 5; // (32,8)
#pragma unroll
        for (int i = 0; i < 4; ++i)
            tile[ty + i * 8][tx] = W[(size_t)(r0 + ty + i * 8) * 1024 + c0 + tx];
        __syncthreads();
#pragma unroll
        for (int i = 0; i < 4; ++i)
            O[(size_t)(c0 + ty + i * 8) * 1024 + r0 + tx] = (bf16)tile[tx][ty + i * 8];
    } else {
        int mb = bid - 10240;
        int lane = tid & 63;
        int wid = (mb * 256 + tid) >> 6;
        int nw = (256 * 256) >> 6;
        const int niter = (4 * 1024 * 1024) / 64;
        for (int i = wid; i < niter; i += nw) {
            int vv = mask[(size_t)i * 64 + lane];
            unsigned long long bb = __ballot(vv != 0);
            if (lane == 0) mbits[i] = bb;
        }
    }
}

// ---------------- projection GEMM (gload_lds staging) ----------------
// z==0/1: head-major Q/K. z==2: writes V^T (B,H,64,S) directly.
__global__ __launch_bounds__(256) void proj_gemm(
    const bf16* __restrict__ Aq, const bf16* __restrict__ Ak, const bf16* __restrict__ Av,
    const bf16* __restrict__ Wq, const bf16* __restrict__ Wk, const bf16* __restrict__ Wv,
    bf16* __restrict__ Oq, bf16* __restrict__ Ok, bf16* __restrict__ OvT)
{
    int z = blockIdx.z;
    const bf16* A = z == 0 ? Aq : z == 1 ? Ak : Av;
    const bf16* WT = z == 0 ? Wq : z == 1 ? Wk : Wv;

    __shared__ bf16 Al[128 * 32];
    __shared__ bf16 Bl[128 * 32];

    int tid = threadIdx.x;
    int w = tid >> 6, l = tid & 63;
    int l15 = l & 15, lg = l >> 4;
    int m0 = blockIdx.y * 128, n0 = blockIdx.x * 128;
    int wm = (w >> 1) * 64, wn = (w & 1) * 64;

    int rr0 = tid >> 2;
    int row0 = rr0 ^ ((rr0 >> 2) & 1);
    int cbe = (((tid & 3) * 16) ^ ((row0 & 3) << 4)) >> 1;
    char* aldst0 = (char*)Al + w * 1024;
    char* aldst1 = (char*)Al + 4096 + w * 1024;
    char* bldst0 = (char*)Bl + w * 1024;
    char* bldst1 = (char*)Bl + 4096 + w * 1024;
    const bf16* asrc0 = A + (size_t)(m0 + row0) * 1024 + cbe;
    const bf16* asrc1 = A + (size_t)(m0 + row0 + 64) * 1024 + cbe;
    const bf16* bsrc0 = WT + (size_t)(n0 + row0) * 1024 + cbe;
    const bf16* bsrc1 = WT + (size_t)(n0 + row0 + 64) * 1024 + cbe;

    const f32x4 fz = {0.f, 0.f, 0.f, 0.f};
    f32x4 acc[4][4];
#pragma unroll
    for (int i = 0; i < 4; ++i)
#pragma unroll
        for (int j = 0; j < 4; ++j) acc[i][j] = fz;

    for (int k0 = 0; k0 < 1024; k0 += 32) {
        gload16(aldst0, asrc0 + k0);
        gload16(aldst1, asrc1 + k0);
        gload16(bldst0, bsrc0 + k0);
        gload16(bldst1, bsrc1 + k0);
        __syncthreads();
        bf16x8 af[4], bv[4];
#pragma unroll
        for (int i = 0; i < 4; ++i)
            af[i] = *(const bf16x8*)((const char*)Al + swz(wm + i * 16 + l15, lg * 16));
#pragma unroll
        for (int j = 0; j < 4; ++j)
            bv[j] = *(const bf16x8*)((const char*)Bl + swz(wn + j * 16 + l15, lg * 16));
#pragma unroll
        for (int i = 0; i < 4; ++i)
#pragma unroll
            for (int j = 0; j < 4; ++j)
                acc[i][j] = __builtin_amdgcn_mfma_f32_16x16x32_bf16(af[i], bv[j], acc[i][j], 0, 0, 0);
        __syncthreads();
    }
    if (z < 2) {
        bf16* O = z == 0 ? Oq : Ok;
#pragma unroll
        for (int i = 0; i < 4; ++i)
#pragma unroll
            for (int j = 0; j < 4; ++j)
#pragma unroll
                for (int r = 0; r < 4; ++r) {
                    int m = m0 + wm + i * 16 + lg * 4 + r;
                    int n = n0 + wn + j * 16 + l15;
                    int bb = m >> 10, s = m & 1023, h = n >> 6, d = n & 63;
                    O[((size_t)(bb * 16 + h) * 1024 + s) * 64 + d] = (bf16)acc[i][j][r];
                }
    } else {
#pragma unroll
        for (int i = 0; i < 4; ++i)
#pragma unroll
            for (int j = 0; j < 4; ++j) {
                int m = m0 + wm + i * 16 + lg * 4;
                int n = n0 + wn + j * 16 + l15;
                int bb = m >> 10, s = m & 1023, h = n >> 6, d = n & 63;
                bf16x4 cv;
#pragma unroll
                for (int r = 0; r < 4; ++r) cv[r] = (bf16)acc[i][j][r];
                *(bf16x4*)(OvT + ((size_t)(bb * 16 + h) * 64 + d) * 1024 + s) = cv;
            }
    }
}

// ---------------- fused attention: phase1 (QK^T+exp+sum+PV+ctx) then
// phase2 (QK^T recompute + normalized nt attn write). One kernel: phase 2 of
// early blocks overlaps phase 1 of late blocks (no inter-kernel grid drain),
// inv passes through LDS (no rowinv global round-trip), Q loads once.
__global__ __launch_bounds__(256, 4) void attn_fused(
    const bf16* __restrict__ Qh, const bf16* __restrict__ Kh,
    const bf16* __restrict__ VhT, const unsigned* __restrict__ mbits,
    bf16* __restrict__ ctx, float* __restrict__ attn_out)
{
    int bh = blockIdx.x;
    int b = bh >> 4, h = bh & 15;
    int tid = threadIdx.x;
    int w = tid >> 6, l = tid & 63;
    int l15 = l & 15, lg = l >> 4;
    int q0 = blockIdx.y * 64 + w * 16;

    const bf16* Qb = Qh + (size_t)bh * 65536;
    const bf16* Kb = Kh + (size_t)bh * 65536;
    const bf16* Vt = VhT + (size_t)bh * 65536;
    const unsigned* mbrow = mbits + ((size_t)b * 1024 + q0 + l15) * 32;

    __shared__ char lds[26624];
    __shared__ float sinv[64];
    // phase 1 layout
    char* const Kl = lds;                      // [64 keys][128B d] swz, 8KB
    char* const Vl = lds + 8192;               // [64 d][128B keys] swz, 8KB
    char* const St = lds + 16384 + w * 2048;   // wave-private [16 q][128B keys]
    // phase 2 layout (reuses lds)
    char* const K0 = lds;
    char* const K1 = lds + 8192;
    char* const S2 = lds + 16384 + w * 2560;   // 16 rows x 160B, wave-private

    const int skr = tid >> 2;            // row 0..63
    const int skb = (tid & 3) * 32;      // byte in 128B row
    const int sks = (skr & 7) << 4;
    const int rsw = (l15 & 7) << 4;
    const int ko0 = (lg * 16) ^ rsw;
    const int ko1 = (64 + lg * 16) ^ rsw;

    bf16x8 qf0 = *(const bf16x8*)(Qb + (size_t)(q0 + l15) * 64 + lg * 8);
    bf16x8 qf1 = *(const bf16x8*)(Qb + (size_t)(q0 + l15) * 64 + 32 + lg * 8);

    const f32x4 fz = {0.f, 0.f, 0.f, 0.f};

    // ================= phase 1 =================
    {   // prologue: stage chunk 0 (K and V)
        const bf16* src = Kb + (size_t)skr * 64 + (skb >> 1);
        bf16x8 a = *(const bf16x8*)src;
        bf16x8 b2 = *(const bf16x8*)(src + 8);
        const bf16* vsrc = Vt + (size_t)skr * 1024 + (skb >> 1);
        bf16x8 va = *(const bf16x8*)vsrc;
        bf16x8 vb = *(const bf16x8*)(vsrc + 8);
        *(bf16x8*)(Kl + skr * 128 + (skb ^ sks)) = a;
        *(bf16x8*)(Kl + skr * 128 + ((skb + 16) ^ sks)) = b2;
        *(bf16x8*)(Vl + skr * 128 + (skb ^ sks)) = va;
        *(bf16x8*)(Vl + skr * 128 + ((skb + 16) ^ sks)) = vb;
    }
    __syncthreads();

    f32x4 oacc[4];
#pragma unroll
    for (int d0 = 0; d0 < 4; ++d0) oacc[d0] = fz;
    float ps = 0.f;

    for (int c = 0; c < 16; ++c) {
        bf16x8 nk0, nk1, nv0, nv1;
        if (c < 15) {   // prefetch chunk c+1 into registers
            const bf16* src = Kb + (size_t)((c + 1) * 64 + skr) * 64 + (skb >> 1);
            nk0 = *(const bf16x8*)src;
            nk1 = *(const bf16x8*)(src + 8);
            const bf16* vsrc = Vt + (size_t)skr * 1024 + (c + 1) * 64 + (skb >> 1);
            nv0 = *(const bf16x8*)vsrc;
            nv1 = *(const bf16x8*)(vsrc + 8);
        }
        u32x2 mw = *(const u32x2*)(mbrow + c * 2);
        f32x4 st[4];
#pragma unroll
        for (int f = 0; f < 4; ++f) st[f] = fz;
#pragma unroll
        for (int f = 0; f < 4; ++f) {
            bf16x8 kf = *(const bf16x8*)(Kl + (f * 16 + l15) * 128 + ko0);
            st[f] = __builtin_amdgcn_mfma_f32_16x16x32_bf16(kf, qf0, st[f], 0, 0, 0);
        }
#pragma unroll
        for (int f = 0; f < 4; ++f) {
            bf16x8 kf = *(const bf16x8*)(Kl + (f * 16 + l15) * 128 + ko1);
            st[f] = __builtin_amdgcn_mfma_f32_16x16x32_bf16(kf, qf1, st[f], 0, 0, 0);
        }
        // masked exp; write P row-major into wave-private St
#pragma unroll
        for (int f = 0; f < 4; ++f) {
            unsigned wb = mw[f >> 1] >> (((f & 1) << 4) + (lg << 2));
            f32x4 o;
            o[0] = (wb & 1u)        ? __expf(st[f][0] * 0.125f) : 0.f;
            o[1] = ((wb >> 1) & 1u) ? __expf(st[f][1] * 0.125f) : 0.f;
            o[2] = ((wb >> 2) & 1u) ? __expf(st[f][2] * 0.125f) : 0.f;
            o[3] = ((wb >> 3) & 1u) ? __expf(st[f][3] * 0.125f) : 0.f;
            ps += (o[0] + o[1]) + (o[2] + o[3]);
            u32x2 pr; pr[0] = packb(o[0], o[1]); pr[1] = packb(o[2], o[3]);
            *(u32x2*)(St + l15 * 128 + ((f * 32 + lg * 8) ^ rsw)) = pr;
        }
        // PV: B-frag = contiguous read of St row q=l15
#pragma unroll
        for (int ks = 0; ks < 2; ++ks) {
            bf16x8 pf = *(const bf16x8*)(St + l15 * 128 + ((ks * 64 + lg * 16) ^ rsw));
#pragma unroll
            for (int d0 = 0; d0 < 4; ++d0) {
                bf16x8 vf = *(const bf16x8*)(Vl + (d0 * 16 + l15) * 128 + ((ks * 64 + lg * 16) ^ rsw));
                oacc[d0] = __builtin_amdgcn_mfma_f32_16x16x32_bf16(vf, pf, oacc[d0], 0, 0, 0);
            }
        }
        __syncthreads();
        if (c < 15) {
            *(bf16x8*)(Kl + skr * 128 + (skb ^ sks)) = nk0;
            *(bf16x8*)(Kl + skr * 128 + ((skb + 16) ^ sks)) = nk1;
            *(bf16x8*)(Vl + skr * 128 + (skb ^ sks)) = nv0;
            *(bf16x8*)(Vl + skr * 128 + ((skb + 16) ^ sks)) = nv1;
        }
        __syncthreads();
    }
    ps += __shfl_xor(ps, 16, 64);
    ps += __shfl_xor(ps, 32, 64);
    float inv = 1.f / ps;
    if (l < 16) sinv[w * 16 + l15] = inv;

    bf16* crow = ctx + ((size_t)(b * 1024 + q0 + l15)) * 1024 + h * 64;
#pragma unroll
    for (int d0 = 0; d0 < 4; ++d0) {
        bf16x4 cv;
#pragma unroll
        for (int r = 0; r < 4; ++r) cv[r] = (bf16)(oacc[d0][r] * inv);
        *(bf16x4*)(crow + d0 * 16 + lg * 4) = cv;
    }
    __syncthreads();   // sinv visible; all phase-1 LDS reads done

    // ================= phase 2 =================
    const int rq = l >> 3;               // 0..7
    const int rk = (l & 7) * 4;          // 0..28
    const float iv0 = sinv[w * 16 + rq];
    const float iv1 = sinv[w * 16 + 8 + rq];
    const unsigned* mb0 = mbits + ((size_t)b * 1024 + q0 + rq) * 32;
    const unsigned* mb1 = mbits + ((size_t)b * 1024 + q0 + 8 + rq) * 32;
    float* abase = attn_out + ((size_t)bh * 1024 + q0) * 1024;

    {   // stage chunk 0 K (L2-hot from phase 1)
        const bf16* src = Kb + (size_t)skr * 64 + (skb >> 1);
        bf16x8 a = *(const bf16x8*)src;
        bf16x8 bb2 = *(const bf16x8*)(src + 8);
        *(bf16x8*)(K0 + skr * 128 + (skb ^ sks)) = a;
        *(bf16x8*)(K0 + skr * 128 + ((skb + 16) ^ sks)) = bb2;
    }

    for (int c = 0; c < 16; ++c) {
        __syncthreads();
        bf16x8 nk0, nk1;
        if (c < 15) {
            const bf16* src = Kb + (size_t)((c + 1) * 64 + skr) * 64 + (skb >> 1);
            nk0 = *(const bf16x8*)src;
            nk1 = *(const bf16x8*)(src + 8);
        }
        u32x2 mw0 = *(const u32x2*)(mb0 + c * 2);
        u32x2 mw1 = *(const u32x2*)(mb1 + c * 2);
        const char* Kc = (c & 1) ? K1 : K0;
        f32x4 st[4];
#pragma unroll
        for (int f = 0; f < 4; ++f) st[f] = fz;
#pragma unroll
        for (int f = 0; f < 4; ++f) {
            bf16x8 kf = *(const bf16x8*)(Kc + (f * 16 + l15) * 128 + ko0);
            st[f] = __builtin_amdgcn_mfma_f32_16x16x32_bf16(kf, qf0, st[f], 0, 0, 0);
        }
#pragma unroll
        for (int f = 0; f < 4; ++f) {
            bf16x8 kf = *(const bf16x8*)(Kc + (f * 16 + l15) * 128 + ko1);
            st[f] = __builtin_amdgcn_mfma_f32_16x16x32_bf16(kf, qf1, st[f], 0, 0, 0);
        }
        const int qsw = (l15 & 7) << 3;
#pragma unroll
        for (int f = 0; f < 4; ++f) {
#pragma unroll
            for (int j = 0; j < 2; ++j) {
                unsigned val = packb(__expf(st[f][2 * j] * 0.125f),
                                     __expf(st[f][2 * j + 1] * 0.125f));
                int kbyte = f * 32 + lg * 8 + j * 4;
                *(unsigned*)(S2 + l15 * 160 + (kbyte ^ qsw)) = val;
            }
        }
#pragma unroll
        for (int ri = 0; ri < 4; ++ri) {
            int qq = rq + 8 * (ri & 1);
            int kk = rk + 32 * (ri >> 1);
            bf16x4 pv4 = *(const bf16x4*)(S2 + qq * 160 + ((kk * 2) ^ ((qq & 7) << 3)));
            unsigned wm = ((ri & 1) ? mw1[ri >> 1] : mw0[ri >> 1]) >> rk;
            float iv = (ri & 1) ? iv1 : iv0;
            f32x4 o;
            o[0] = (wm & 1u)        ? (float)pv4[0] * iv : 0.f;
            o[1] = ((wm >> 1) & 1u) ? (float)pv4[1] * iv : 0.f;
            o[2] = ((wm >> 2) & 1u) ? (float)pv4[2] * iv : 0.f;
            o[3] = ((wm >> 3) & 1u) ? (float)pv4[3] * iv : 0.f;
            // nontemporal: attn is write-once streaming output
            __builtin_nontemporal_store(o, (f32x4*)(abase + (size_t)qq * 1024 + c * 64 + kk));
        }
        if (c < 15) {
            char* kdst = ((c & 1) ? K0 : K1) + skr * 128;
            *(bf16x8*)(kdst + (skb ^ sks)) = nk0;
            *(bf16x8*)(kdst + ((skb + 16) ^ sks)) = nk1;
        }
    }
}

// ---------------- FC GEMM + residual -> preLN f32 ----------------
__global__ __launch_bounds__(256) void fc_gemm(
    const bf16* __restrict__ ctx, const bf16* __restrict__ WT,
    const float* __restrict__ resid, float* __restrict__ preLN)
{
    __shared__ bf16 Al[128 * 32];
    __shared__ bf16 Bl[128 * 32];
    int tid = threadIdx.x;
    int w = tid >> 6, l = tid & 63;
    int l15 = l & 15, lg = l >> 4;
    int m0 = blockIdx.y * 128, n0 = blockIdx.x * 128;
    int wm = (w >> 1) * 64, wn = (w & 1) * 64;

    int rr0 = tid >> 2;
    int row0 = rr0 ^ ((rr0 >> 2) & 1);
    int cbe = (((tid & 3) * 16) ^ ((row0 & 3) << 4)) >> 1;
    char* aldst0 = (char*)Al + w * 1024;
    char* aldst1 = (char*)Al + 4096 + w * 1024;
    char* bldst0 = (char*)Bl + w * 1024;
    char* bldst1 = (char*)Bl + 4096 + w * 1024;
    const bf16* asrc0 = ctx + (size_t)(m0 + row0) * 1024 + cbe;
    const bf16* asrc1 = ctx + (size_t)(m0 + row0 + 64) * 1024 + cbe;
    const bf16* bsrc0 = WT + (size_t)(n0 + row0) * 1024 + cbe;
    const bf16* bsrc1 = WT + (size_t)(n0 + row0 + 64) * 1024 + cbe;

    const f32x4 fz = {0.f, 0.f, 0.f, 0.f};
    f32x4 acc[4][4];
#pragma unroll
    for (int i = 0; i < 4; ++i)
#pragma unroll
        for (int j = 0; j < 4; ++j) acc[i][j] = fz;

    for (int k0 = 0; k0 < 1024; k0 += 32) {
        gload16(aldst0, asrc0 + k0);
        gload16(aldst1, asrc1 + k0);
        gload16(bldst0, bsrc0 + k0);
        gload16(bldst1, bsrc1 + k0);
        __syncthreads();
        bf16x8 af[4], bv[4];
#pragma unroll
        for (int i = 0; i < 4; ++i)
            af[i] = *(const bf16x8*)((const char*)Al + swz(wm + i * 16 + l15, lg * 16));
#pragma unroll
        for (int j = 0; j < 4; ++j)
            bv[j] = *(const bf16x8*)((const char*)Bl + swz(wn + j * 16 + l15, lg * 16));
#pragma unroll
        for (int i = 0; i < 4; ++i)
#pragma unroll
            for (int j = 0; j < 4; ++j)
                acc[i][j] = __builtin_amdgcn_mfma_f32_16x16x32_bf16(af[i], bv[j], acc[i][j], 0, 0, 0);
        __syncthreads();
    }
#pragma unroll
    for (int i = 0; i < 4; ++i)
#pragma unroll
        for (int j = 0; j < 4; ++j)
#pragma unroll
            for (int r = 0; r < 4; ++r) {
                int m = m0 + wm + i * 16 + lg * 4 + r;
                int n = n0 + wn + j * 16 + l15;
                preLN[(size_t)m * 1024 + n] = acc[i][j][r] + resid[(size_t)m * 1024 + n];
            }
}

// ---------------- LayerNorm ----------------
__global__ __launch_bounds__(256) void ln_kernel(
    const float* __restrict__ x, const float* __restrict__ gamma,
    const float* __restrict__ beta, float* __restrict__ out)
{
    int row = blockIdx.x, t = threadIdx.x;
    const float* xr = x + (size_t)row * 1024;
    f32x4 v = *(const f32x4*)(xr + t * 4);
    float s = v[0] + v[1] + v[2] + v[3];
    float s2 = v[0] * v[0] + v[1] * v[1] + v[2] * v[2] + v[3] * v[3];
#pragma unroll
    for (int m = 1; m < 64; m <<= 1) {
        s += __shfl_xor(s, m, 64);
        s2 += __shfl_xor(s2, m, 64);
    }
    __shared__ float rs[4], rs2[4];
    if ((t & 63) == 0) { rs[t >> 6] = s; rs2[t >> 6] = s2; }
    __syncthreads();
    float S = rs[0] + rs[1] + rs[2] + rs[3];
    float S2 = rs2[0] + rs2[1] + rs2[2] + rs2[3];
    float mu = S * (1.f / 1024.f);
    float var = S2 * (1.f / 1024.f) - mu * mu;
    float rinv = rsqrtf(var + 1e-6f);
    f32x4 g = *(const f32x4*)(gamma + t * 4);
    f32x4 bb = *(const f32x4*)(beta + t * 4);
    f32x4 o;
#pragma unroll
    for (int j = 0; j < 4; ++j) o[j] = (v[j] - mu) * rinv * g[j] + bb[j];
    // out is a write-once streaming output (never re-read on device)
    __builtin_nontemporal_store(o, (f32x4*)(out + (size_t)row * 1024 + t * 4));
}

extern "C" void kernel_launch(void* const* d_in, const int* in_sizes, int n_in,
                              void* d_out, int out_size, void* d_ws, size_t ws_size,
                              hipStream_t stream) {
    const float* q     = (const float*)d_in[0];
    const float* k     = (const float*)d_in[1];
    const float* v     = (const float*)d_in[2];
    const int*   mask  = (const int*)d_in[3];
    const float* w_qs  = (const float*)d_in[4];
    const float* w_ks  = (const float*)d_in[5];
    const float* w_vs  = (const float*)d_in[6];
    const float* w_fc  = (const float*)d_in[7];
    const float* gamma = (const float*)d_in[8];
    const float* beta  = (const float*)d_in[9];

    float* out  = (float*)d_out;
    float* attn = out + (size_t)4 * 1024 * 1024; // second tuple output

    char* ws = (char*)d_ws;
    bf16* wqT   = (bf16*)(ws + (0ull  << 20));
    bf16* wkT   = (bf16*)(ws + (2ull  << 20));
    bf16* wvT   = (bf16*)(ws + (4ull  << 20));
    bf16* wfcT  = (bf16*)(ws + (6ull  << 20));
    bf16* Qh    = (bf16*)(ws + (8ull  << 20));
    bf16* Kh    = (bf16*)(ws + (16ull << 20));
    bf16* VhT   = (bf16*)(ws + (32ull << 20));
    bf16* ctx   = (bf16*)(ws + (40ull << 20));
    float* preLN = (float*)(ws + (48ull << 20));
    unsigned long long* mbits = (unsigned long long*)(ws + (25ull << 20)); // 512KB

    // bf16 copies of q/k/v live in the attn output region (dead until
    // attn_fused phase 2 overwrites every byte; proj reads them first).
    char* scratch = (char*)attn;
    bf16* qb = (bf16*)scratch;
    bf16* kb = qb + (size_t)4 * 1024 * 1024;
    bf16* vb = kb + (size_t)4 * 1024 * 1024;

    prep_kernel<<<10496, 256, 0, stream>>>(q, k, v, qb, kb, vb,
                                           w_qs, w_ks, w_vs, w_fc,
                                           wqT, wkT, wvT, wfcT,
                                           mask, mbits);
    proj_gemm<<<dim3(8, 32, 3), 256, 0, stream>>>(qb, kb, vb, wqT, wkT, wvT,
                                                  Qh, Kh, VhT);
    attn_fused<<<dim3(64, 16), 256, 0, stream>>>(Qh, Kh, VhT, (const unsigned*)mbits,
                                                 ctx, attn);
    fc_gemm<<<dim3(8, 32), 256, 0, stream>>>(ctx, wfcT, q, preLN);
    ln_kernel<<<4096, 256, 0, stream>>>(preLN, gamma, beta, out);
}

// Round 19
// 181.709 us; speedup vs baseline: 1.0815x; 1.0727x over previous
//
#include <hip/hip_runtime.h>
#include <stdint.h>

typedef __bf16 bf16;
typedef __bf16 bf16x2 __attribute__((ext_vector_type(2)));
typedef __bf16 bf16x4 __attribute__((ext_vector_type(4)));
typedef __bf16 bf16x8 __attribute__((ext_vector_type(8)));
typedef float f32x4 __attribute__((ext_vector_type(4)));
typedef unsigned u32x2 __attribute__((ext_vector_type(2)));

// XOR swizzle for [rows][32] bf16 LDS tiles (64B row stride).
__device__ __forceinline__ int swz(int row, int colb) {
    return (row * 64 + colb) ^ ((row & 7) << 4);
}

__device__ __forceinline__ unsigned packb(float a, float b) {
    bf16x2 t; t[0] = (bf16)a; t[1] = (bf16)b;
    return __builtin_bit_cast(unsigned, t);
}

// async global->LDS 16B copy (dest = wave-uniform base + lane*16)
__device__ __forceinline__ void gload16(void* lds, const void* g) {
    __builtin_amdgcn_global_load_lds(
        (const __attribute__((address_space(1))) void*)g,
        (__attribute__((address_space(3))) void*)lds, 16, 0, 0);
}

// ---------------- prep: q/k/v cvt + weight transpose + mask pack (one launch) --
__global__ __launch_bounds__(256) void prep_kernel(
    const float* __restrict__ q, const float* __restrict__ k, const float* __restrict__ v,
    bf16* __restrict__ oq, bf16* __restrict__ ok, bf16* __restrict__ ov,
    const float* __restrict__ w0, const float* __restrict__ w1,
    const float* __restrict__ w2, const float* __restrict__ w3,
    bf16* __restrict__ t0, bf16* __restrict__ t1,
    bf16* __restrict__ t2, bf16* __restrict__ t3,
    const int* __restrict__ mask, unsigned long long* __restrict__ mbits)
{
    int bid = blockIdx.x;
    int tid = threadIdx.x;
    __shared__ float tile[32][33];

    if (bid < 6144) {
        int z = bid >> 11;
        int bx = bid & 2047;
        const float* src = z == 0 ? q : z == 1 ? k : v;
        bf16* dst = z == 0 ? oq : z == 1 ? ok : ov;
        size_t i = ((size_t)bx * 256 + tid) * 8;
        f32x4 a = *(const f32x4*)(src + i);
        f32x4 b = *(const f32x4*)(src + i + 4);
        bf16x8 o;
#pragma unroll
        for (int j = 0; j < 4; ++j) { o[j] = (bf16)a[j]; o[4 + j] = (bf16)b[j]; }
        *(bf16x8*)(dst + i) = o;
    } else if (bid < 10240) {
        int wid = bid - 6144;
        int z = wid >> 10;
        int t = wid & 1023;
        const float* W = z == 0 ? w0 : z == 1 ? w1 : z == 2 ? w2 : w3;
        bf16* O = z == 0 ? t0 : z == 1 ? t1 : z == 2 ? t2 : t3;
        int c0 = (t & 31) * 32, r0 = (t >> 5) * 32;
        int tx = tid & 31, ty = tid >> 5; // (32,8)
#pragma unroll
        for (int i = 0; i < 4; ++i)
            tile[ty + i * 8][tx] = W[(size_t)(r0 + ty + i * 8) * 1024 + c0 + tx];
        __syncthreads();
#pragma unroll
        for (int i = 0; i < 4; ++i)
            O[(size_t)(c0 + ty + i * 8) * 1024 + r0 + tx] = (bf16)tile[tx][ty + i * 8];
    } else {
        int mb = bid - 10240;
        int lane = tid & 63;
        int wid = (mb * 256 + tid) >> 6;
        int nw = (256 * 256) >> 6;
        const int niter = (4 * 1024 * 1024) / 64;
        for (int i = wid; i < niter; i += nw) {
            int vv = mask[(size_t)i * 64 + lane];
            unsigned long long bb = __ballot(vv != 0);
            if (lane == 0) mbits[i] = bb;
        }
    }
}

// ---------------- projection GEMM (gload_lds staging) ----------------
// z==0/1: head-major Q/K. z==2: writes V^T (B,H,64,S) directly.
__global__ __launch_bounds__(256) void proj_gemm(
    const bf16* __restrict__ Aq, const bf16* __restrict__ Ak, const bf16* __restrict__ Av,
    const bf16* __restrict__ Wq, const bf16* __restrict__ Wk, const bf16* __restrict__ Wv,
    bf16* __restrict__ Oq, bf16* __restrict__ Ok, bf16* __restrict__ OvT)
{
    int z = blockIdx.z;
    const bf16* A = z == 0 ? Aq : z == 1 ? Ak : Av;
    const bf16* WT = z == 0 ? Wq : z == 1 ? Wk : Wv;

    __shared__ bf16 Al[128 * 32];
    __shared__ bf16 Bl[128 * 32];

    int tid = threadIdx.x;
    int w = tid >> 6, l = tid & 63;
    int l15 = l & 15, lg = l >> 4;
    int m0 = blockIdx.y * 128, n0 = blockIdx.x * 128;
    int wm = (w >> 1) * 64, wn = (w & 1) * 64;

    int rr0 = tid >> 2;
    int row0 = rr0 ^ ((rr0 >> 2) & 1);
    int cbe = (((tid & 3) * 16) ^ ((row0 & 3) << 4)) >> 1;
    char* aldst0 = (char*)Al + w * 1024;
    char* aldst1 = (char*)Al + 4096 + w * 1024;
    char* bldst0 = (char*)Bl + w * 1024;
    char* bldst1 = (char*)Bl + 4096 + w * 1024;
    const bf16* asrc0 = A + (size_t)(m0 + row0) * 1024 + cbe;
    const bf16* asrc1 = A + (size_t)(m0 + row0 + 64) * 1024 + cbe;
    const bf16* bsrc0 = WT + (size_t)(n0 + row0) * 1024 + cbe;
    const bf16* bsrc1 = WT + (size_t)(n0 + row0 + 64) * 1024 + cbe;

    const f32x4 fz = {0.f, 0.f, 0.f, 0.f};
    f32x4 acc[4][4];
#pragma unroll
    for (int i = 0; i < 4; ++i)
#pragma unroll
        for (int j = 0; j < 4; ++j) acc[i][j] = fz;

    for (int k0 = 0; k0 < 1024; k0 += 32) {
        gload16(aldst0, asrc0 + k0);
        gload16(aldst1, asrc1 + k0);
        gload16(bldst0, bsrc0 + k0);
        gload16(bldst1, bsrc1 + k0);
        __syncthreads();
        bf16x8 af[4], bv[4];
#pragma unroll
        for (int i = 0; i < 4; ++i)
            af[i] = *(const bf16x8*)((const char*)Al + swz(wm + i * 16 + l15, lg * 16));
#pragma unroll
        for (int j = 0; j < 4; ++j)
            bv[j] = *(const bf16x8*)((const char*)Bl + swz(wn + j * 16 + l15, lg * 16));
#pragma unroll
        for (int i = 0; i < 4; ++i)
#pragma unroll
            for (int j = 0; j < 4; ++j)
                acc[i][j] = __builtin_amdgcn_mfma_f32_16x16x32_bf16(af[i], bv[j], acc[i][j], 0, 0, 0);
        __syncthreads();
    }
    if (z < 2) {
        bf16* O = z == 0 ? Oq : Ok;
#pragma unroll
        for (int i = 0; i < 4; ++i)
#pragma unroll
            for (int j = 0; j < 4; ++j)
#pragma unroll
                for (int r = 0; r < 4; ++r) {
                    int m = m0 + wm + i * 16 + lg * 4 + r;
                    int n = n0 + wn + j * 16 + l15;
                    int bb = m >> 10, s = m & 1023, h = n >> 6, d = n & 63;
                    O[((size_t)(bb * 16 + h) * 1024 + s) * 64 + d] = (bf16)acc[i][j][r];
                }
    } else {
#pragma unroll
        for (int i = 0; i < 4; ++i)
#pragma unroll
            for (int j = 0; j < 4; ++j) {
                int m = m0 + wm + i * 16 + lg * 4;
                int n = n0 + wn + j * 16 + l15;
                int bb = m >> 10, s = m & 1023, h = n >> 6, d = n & 63;
                bf16x4 cv;
#pragma unroll
                for (int r = 0; r < 4; ++r) cv[r] = (bf16)acc[i][j][r];
                *(bf16x4*)(OvT + ((size_t)(bb * 16 + h) * 64 + d) * 1024 + s) = cv;
            }
    }
}

// ---------------- fused attention (R13) + XCD-aware block swizzle -------------
// grid = 1024 linear blocks. Bijective swizzle wgid=(bid&7)*128+(bid>>3) makes
// each XCD (round-robin on bid) serve 8 consecutive bh only -> 2MB K/V per XCD
// L2 (vs 16MB working set without swizzle); phase-2 K refetch hits hot L2.
__global__ __launch_bounds__(256, 4) void attn_fused(
    const bf16* __restrict__ Qh, const bf16* __restrict__ Kh,
    const bf16* __restrict__ VhT, const unsigned* __restrict__ mbits,
    bf16* __restrict__ ctx, float* __restrict__ attn_out)
{
    int bid = blockIdx.x;
    int wgid = (bid & 7) * 128 + (bid >> 3);   // bijective on [0,1024)
    int bh = wgid >> 4;
    int b = bh >> 4, h = bh & 15;
    int tid = threadIdx.x;
    int w = tid >> 6, l = tid & 63;
    int l15 = l & 15, lg = l >> 4;
    int q0 = (wgid & 15) * 64 + w * 16;

    const bf16* Qb = Qh + (size_t)bh * 65536;
    const bf16* Kb = Kh + (size_t)bh * 65536;
    const bf16* Vt = VhT + (size_t)bh * 65536;
    const unsigned* mbrow = mbits + ((size_t)b * 1024 + q0 + l15) * 32;

    __shared__ char lds[26624];
    __shared__ float sinv[64];
    // phase 1 layout
    char* const Kl = lds;                      // [64 keys][128B d] swz, 8KB
    char* const Vl = lds + 8192;               // [64 d][128B keys] swz, 8KB
    char* const St = lds + 16384 + w * 2048;   // wave-private [16 q][128B keys]
    // phase 2 layout (reuses lds)
    char* const K0 = lds;
    char* const K1 = lds + 8192;
    char* const S2 = lds + 16384 + w * 2560;   // 16 rows x 160B, wave-private

    const int skr = tid >> 2;            // row 0..63
    const int skb = (tid & 3) * 32;      // byte in 128B row
    const int sks = (skr & 7) << 4;
    const int rsw = (l15 & 7) << 4;
    const int ko0 = (lg * 16) ^ rsw;
    const int ko1 = (64 + lg * 16) ^ rsw;

    bf16x8 qf0 = *(const bf16x8*)(Qb + (size_t)(q0 + l15) * 64 + lg * 8);
    bf16x8 qf1 = *(const bf16x8*)(Qb + (size_t)(q0 + l15) * 64 + 32 + lg * 8);

    const f32x4 fz = {0.f, 0.f, 0.f, 0.f};

    // ================= phase 1 =================
    {   // prologue: stage chunk 0 (K and V)
        const bf16* src = Kb + (size_t)skr * 64 + (skb >> 1);
        bf16x8 a = *(const bf16x8*)src;
        bf16x8 b2 = *(const bf16x8*)(src + 8);
        const bf16* vsrc = Vt + (size_t)skr * 1024 + (skb >> 1);
        bf16x8 va = *(const bf16x8*)vsrc;
        bf16x8 vb = *(const bf16x8*)(vsrc + 8);
        *(bf16x8*)(Kl + skr * 128 + (skb ^ sks)) = a;
        *(bf16x8*)(Kl + skr * 128 + ((skb + 16) ^ sks)) = b2;
        *(bf16x8*)(Vl + skr * 128 + (skb ^ sks)) = va;
        *(bf16x8*)(Vl + skr * 128 + ((skb + 16) ^ sks)) = vb;
    }
    __syncthreads();

    f32x4 oacc[4];
#pragma unroll
    for (int d0 = 0; d0 < 4; ++d0) oacc[d0] = fz;
    float ps = 0.f;

    for (int c = 0; c < 16; ++c) {
        bf16x8 nk0, nk1, nv0, nv1;
        if (c < 15) {   // prefetch chunk c+1 into registers
            const bf16* src = Kb + (size_t)((c + 1) * 64 + skr) * 64 + (skb >> 1);
            nk0 = *(const bf16x8*)src;
            nk1 = *(const bf16x8*)(src + 8);
            const bf16* vsrc = Vt + (size_t)skr * 1024 + (c + 1) * 64 + (skb >> 1);
            nv0 = *(const bf16x8*)vsrc;
            nv1 = *(const bf16x8*)(vsrc + 8);
        }
        u32x2 mw = *(const u32x2*)(mbrow + c * 2);
        f32x4 st[4];
#pragma unroll
        for (int f = 0; f < 4; ++f) st[f] = fz;
#pragma unroll
        for (int f = 0; f < 4; ++f) {
            bf16x8 kf = *(const bf16x8*)(Kl + (f * 16 + l15) * 128 + ko0);
            st[f] = __builtin_amdgcn_mfma_f32_16x16x32_bf16(kf, qf0, st[f], 0, 0, 0);
        }
#pragma unroll
        for (int f = 0; f < 4; ++f) {
            bf16x8 kf = *(const bf16x8*)(Kl + (f * 16 + l15) * 128 + ko1);
            st[f] = __builtin_amdgcn_mfma_f32_16x16x32_bf16(kf, qf1, st[f], 0, 0, 0);
        }
        // masked exp; write P row-major into wave-private St
#pragma unroll
        for (int f = 0; f < 4; ++f) {
            unsigned wb = mw[f >> 1] >> (((f & 1) << 4) + (lg << 2));
            f32x4 o;
            o[0] = (wb & 1u)        ? __expf(st[f][0] * 0.125f) : 0.f;
            o[1] = ((wb >> 1) & 1u) ? __expf(st[f][1] * 0.125f) : 0.f;
            o[2] = ((wb >> 2) & 1u) ? __expf(st[f][2] * 0.125f) : 0.f;
            o[3] = ((wb >> 3) & 1u) ? __expf(st[f][3] * 0.125f) : 0.f;
            ps += (o[0] + o[1]) + (o[2] + o[3]);
            u32x2 pr; pr[0] = packb(o[0], o[1]); pr[1] = packb(o[2], o[3]);
            *(u32x2*)(St + l15 * 128 + ((f * 32 + lg * 8) ^ rsw)) = pr;
        }
        // PV: B-frag = contiguous read of St row q=l15
#pragma unroll
        for (int ks = 0; ks < 2; ++ks) {
            bf16x8 pf = *(const bf16x8*)(St + l15 * 128 + ((ks * 64 + lg * 16) ^ rsw));
#pragma unroll
            for (int d0 = 0; d0 < 4; ++d0) {
                bf16x8 vf = *(const bf16x8*)(Vl + (d0 * 16 + l15) * 128 + ((ks * 64 + lg * 16) ^ rsw));
                oacc[d0] = __builtin_amdgcn_mfma_f32_16x16x32_bf16(vf, pf, oacc[d0], 0, 0, 0);
            }
        }
        __syncthreads();
        if (c < 15) {
            *(bf16x8*)(Kl + skr * 128 + (skb ^ sks)) = nk0;
            *(bf16x8*)(Kl + skr * 128 + ((skb + 16) ^ sks)) = nk1;
            *(bf16x8*)(Vl + skr * 128 + (skb ^ sks)) = nv0;
            *(bf16x8*)(Vl + skr * 128 + ((skb + 16) ^ sks)) = nv1;
        }
        __syncthreads();
    }
    ps += __shfl_xor(ps, 16, 64);
    ps += __shfl_xor(ps, 32, 64);
    float inv = 1.f / ps;
    if (l < 16) sinv[w * 16 + l15] = inv;

    bf16* crow = ctx + ((size_t)(b * 1024 + q0 + l15)) * 1024 + h * 64;
#pragma unroll
    for (int d0 = 0; d0 < 4; ++d0) {
        bf16x4 cv;
#pragma unroll
        for (int r = 0; r < 4; ++r) cv[r] = (bf16)(oacc[d0][r] * inv);
        *(bf16x4*)(crow + d0 * 16 + lg * 4) = cv;
    }
    __syncthreads();   // sinv visible; all phase-1 LDS reads done

    // ================= phase 2 =================
    const int rq = l >> 3;               // 0..7
    const int rk = (l & 7) * 4;          // 0..28
    const float iv0 = sinv[w * 16 + rq];
    const float iv1 = sinv[w * 16 + 8 + rq];
    const unsigned* mb0 = mbits + ((size_t)b * 1024 + q0 + rq) * 32;
    const unsigned* mb1 = mbits + ((size_t)b * 1024 + q0 + 8 + rq) * 32;
    float* abase = attn_out + ((size_t)bh * 1024 + q0) * 1024;

    {   // stage chunk 0 K (L2-hot from phase 1)
        const bf16* src = Kb + (size_t)skr * 64 + (skb >> 1);
        bf16x8 a = *(const bf16x8*)src;
        bf16x8 bb2 = *(const bf16x8*)(src + 8);
        *(bf16x8*)(K0 + skr * 128 + (skb ^ sks)) = a;
        *(bf16x8*)(K0 + skr * 128 + ((skb + 16) ^ sks)) = bb2;
    }

    for (int c = 0; c < 16; ++c) {
        __syncthreads();
        bf16x8 nk0, nk1;
        if (c < 15) {
            const bf16* src = Kb + (size_t)((c + 1) * 64 + skr) * 64 + (skb >> 1);
            nk0 = *(const bf16x8*)src;
            nk1 = *(const bf16x8*)(src + 8);
        }
        u32x2 mw0 = *(const u32x2*)(mb0 + c * 2);
        u32x2 mw1 = *(const u32x2*)(mb1 + c * 2);
        const char* Kc = (c & 1) ? K1 : K0;
        f32x4 st[4];
#pragma unroll
        for (int f = 0; f < 4; ++f) st[f] = fz;
#pragma unroll
        for (int f = 0; f < 4; ++f) {
            bf16x8 kf = *(const bf16x8*)(Kc + (f * 16 + l15) * 128 + ko0);
            st[f] = __builtin_amdgcn_mfma_f32_16x16x32_bf16(kf, qf0, st[f], 0, 0, 0);
        }
#pragma unroll
        for (int f = 0; f < 4; ++f) {
            bf16x8 kf = *(const bf16x8*)(Kc + (f * 16 + l15) * 128 + ko1);
            st[f] = __builtin_amdgcn_mfma_f32_16x16x32_bf16(kf, qf1, st[f], 0, 0, 0);
        }
        const int qsw = (l15 & 7) << 3;
#pragma unroll
        for (int f = 0; f < 4; ++f) {
#pragma unroll
            for (int j = 0; j < 2; ++j) {
                unsigned val = packb(__expf(st[f][2 * j] * 0.125f),
                                     __expf(st[f][2 * j + 1] * 0.125f));
                int kbyte = f * 32 + lg * 8 + j * 4;
                *(unsigned*)(S2 + l15 * 160 + (kbyte ^ qsw)) = val;
            }
        }
#pragma unroll
        for (int ri = 0; ri < 4; ++ri) {
            int qq = rq + 8 * (ri & 1);
            int kk = rk + 32 * (ri >> 1);
            bf16x4 pv4 = *(const bf16x4*)(S2 + qq * 160 + ((kk * 2) ^ ((qq & 7) << 3)));
            unsigned wm = ((ri & 1) ? mw1[ri >> 1] : mw0[ri >> 1]) >> rk;
            float iv = (ri & 1) ? iv1 : iv0;
            f32x4 o;
            o[0] = (wm & 1u)        ? (float)pv4[0] * iv : 0.f;
            o[1] = ((wm >> 1) & 1u) ? (float)pv4[1] * iv : 0.f;
            o[2] = ((wm >> 2) & 1u) ? (float)pv4[2] * iv : 0.f;
            o[3] = ((wm >> 3) & 1u) ? (float)pv4[3] * iv : 0.f;
            // nontemporal: attn is write-once streaming output
            __builtin_nontemporal_store(o, (f32x4*)(abase + (size_t)qq * 1024 + c * 64 + kk));
        }
        if (c < 15) {
            char* kdst = ((c & 1) ? K0 : K1) + skr * 128;
            *(bf16x8*)(kdst + (skb ^ sks)) = nk0;
            *(bf16x8*)(kdst + ((skb + 16) ^ sks)) = nk1;
        }
    }
}

// ---------------- FC GEMM + residual -> preLN f32 ----------------
__global__ __launch_bounds__(256) void fc_gemm(
    const bf16* __restrict__ ctx, const bf16* __restrict__ WT,
    const float* __restrict__ resid, float* __restrict__ preLN)
{
    __shared__ bf16 Al[128 * 32];
    __shared__ bf16 Bl[128 * 32];
    int tid = threadIdx.x;
    int w = tid >> 6, l = tid & 63;
    int l15 = l & 15, lg = l >> 4;
    int m0 = blockIdx.y * 128, n0 = blockIdx.x * 128;
    int wm = (w >> 1) * 64, wn = (w & 1) * 64;

    int rr0 = tid >> 2;
    int row0 = rr0 ^ ((rr0 >> 2) & 1);
    int cbe = (((tid & 3) * 16) ^ ((row0 & 3) << 4)) >> 1;
    char* aldst0 = (char*)Al + w * 1024;
    char* aldst1 = (char*)Al + 4096 + w * 1024;
    char* bldst0 = (char*)Bl + w * 1024;
    char* bldst1 = (char*)Bl + 4096 + w * 1024;
    const bf16* asrc0 = ctx + (size_t)(m0 + row0) * 1024 + cbe;
    const bf16* asrc1 = ctx + (size_t)(m0 + row0 + 64) * 1024 + cbe;
    const bf16* bsrc0 = WT + (size_t)(n0 + row0) * 1024 + cbe;
    const bf16* bsrc1 = WT + (size_t)(n0 + row0 + 64) * 1024 + cbe;

    const f32x4 fz = {0.f, 0.f, 0.f, 0.f};
    f32x4 acc[4][4];
#pragma unroll
    for (int i = 0; i < 4; ++i)
#pragma unroll
        for (int j = 0; j < 4; ++j) acc[i][j] = fz;

    for (int k0 = 0; k0 < 1024; k0 += 32) {
        gload16(aldst0, asrc0 + k0);
        gload16(aldst1, asrc1 + k0);
        gload16(bldst0, bsrc0 + k0);
        gload16(bldst1, bsrc1 + k0);
        __syncthreads();
        bf16x8 af[4], bv[4];
#pragma unroll
        for (int i = 0; i < 4; ++i)
            af[i] = *(const bf16x8*)((const char*)Al + swz(wm + i * 16 + l15, lg * 16));
#pragma unroll
        for (int j = 0; j < 4; ++j)
            bv[j] = *(const bf16x8*)((const char*)Bl + swz(wn + j * 16 + l15, lg * 16));
#pragma unroll
        for (int i = 0; i < 4; ++i)
#pragma unroll
            for (int j = 0; j < 4; ++j)
                acc[i][j] = __builtin_amdgcn_mfma_f32_16x16x32_bf16(af[i], bv[j], acc[i][j], 0, 0, 0);
        __syncthreads();
    }
#pragma unroll
    for (int i = 0; i < 4; ++i)
#pragma unroll
        for (int j = 0; j < 4; ++j)
#pragma unroll
            for (int r = 0; r < 4; ++r) {
                int m = m0 + wm + i * 16 + lg * 4 + r;
                int n = n0 + wn + j * 16 + l15;
                preLN[(size_t)m * 1024 + n] = acc[i][j][r] + resid[(size_t)m * 1024 + n];
            }
}

// ---------------- LayerNorm ----------------
__global__ __launch_bounds__(256) void ln_kernel(
    const float* __restrict__ x, const float* __restrict__ gamma,
    const float* __restrict__ beta, float* __restrict__ out)
{
    int row = blockIdx.x, t = threadIdx.x;
    const float* xr = x + (size_t)row * 1024;
    f32x4 v = *(const f32x4*)(xr + t * 4);
    float s = v[0] + v[1] + v[2] + v[3];
    float s2 = v[0] * v[0] + v[1] * v[1] + v[2] * v[2] + v[3] * v[3];
#pragma unroll
    for (int m = 1; m < 64; m <<= 1) {
        s += __shfl_xor(s, m, 64);
        s2 += __shfl_xor(s2, m, 64);
    }
    __shared__ float rs[4], rs2[4];
    if ((t & 63) == 0) { rs[t >> 6] = s; rs2[t >> 6] = s2; }
    __syncthreads();
    float S = rs[0] + rs[1] + rs[2] + rs[3];
    float S2 = rs2[0] + rs2[1] + rs2[2] + rs2[3];
    float mu = S * (1.f / 1024.f);
    float var = S2 * (1.f / 1024.f) - mu * mu;
    float rinv = rsqrtf(var + 1e-6f);
    f32x4 g = *(const f32x4*)(gamma + t * 4);
    f32x4 bb = *(const f32x4*)(beta + t * 4);
    f32x4 o;
#pragma unroll
    for (int j = 0; j < 4; ++j) o[j] = (v[j] - mu) * rinv * g[j] + bb[j];
    // out is a write-once streaming output (never re-read on device)
    __builtin_nontemporal_store(o, (f32x4*)(out + (size_t)row * 1024 + t * 4));
}

extern "C" void kernel_launch(void* const* d_in, const int* in_sizes, int n_in,
                              void* d_out, int out_size, void* d_ws, size_t ws_size,
                              hipStream_t stream) {
    const float* q     = (const float*)d_in[0];
    const float* k     = (const float*)d_in[1];
    const float* v     = (const float*)d_in[2];
    const int*   mask  = (const int*)d_in[3];
    const float* w_qs  = (const float*)d_in[4];
    const float* w_ks  = (const float*)d_in[5];
    const float* w_vs  = (const float*)d_in[6];
    const float* w_fc  = (const float*)d_in[7];
    const float* gamma = (const float*)d_in[8];
    const float* beta  = (const float*)d_in[9];

    float* out  = (float*)d_out;
    float* attn = out + (size_t)4 * 1024 * 1024; // second tuple output

    char* ws = (char*)d_ws;
    bf16* wqT   = (bf16*)(ws + (0ull  << 20));
    bf16* wkT   = (bf16*)(ws + (2ull  << 20));
    bf16* wvT   = (bf16*)(ws + (4ull  << 20));
    bf16* wfcT  = (bf16*)(ws + (6ull  << 20));
    bf16* Qh    = (bf16*)(ws + (8ull  << 20));
    bf16* Kh    = (bf16*)(ws + (16ull << 20));
    bf16* VhT   = (bf16*)(ws + (32ull << 20));
    bf16* ctx   = (bf16*)(ws + (40ull << 20));
    float* preLN = (float*)(ws + (48ull << 20));
    unsigned long long* mbits = (unsigned long long*)(ws + (25ull << 20)); // 512KB

    // bf16 copies of q/k/v live in the attn output region (dead until
    // attn_fused phase 2 overwrites every byte; proj reads them first).
    char* scratch = (char*)attn;
    bf16* qb = (bf16*)scratch;
    bf16* kb = qb + (size_t)4 * 1024 * 1024;
    bf16* vb = kb + (size_t)4 * 1024 * 1024;

    prep_kernel<<<10496, 256, 0, stream>>>(q, k, v, qb, kb, vb,
                                           w_qs, w_ks, w_vs, w_fc,
                                           wqT, wkT, wvT, wfcT,
                                           mask, mbits);
    proj_gemm<<<dim3(8, 32, 3), 256, 0, stream>>>(qb, kb, vb, wqT, wkT, wvT,
                                                  Qh, Kh, VhT);
    attn_fused<<<1024, 256, 0, stream>>>(Qh, Kh, VhT, (const unsigned*)mbits,
                                         ctx, attn);
    fc_gemm<<<dim3(8, 32), 256, 0, stream>>>(ctx, wfcT, q, preLN);
    ln_kernel<<<4096, 256, 0, stream>>>(preLN, gamma, beta, out);
}

// Round 20
// 177.064 us; speedup vs baseline: 1.1099x; 1.0262x over previous
//
#include <hip/hip_runtime.h>
#include <stdint.h>

typedef __bf16 bf16;
typedef __bf16 bf16x2 __attribute__((ext_vector_type(2)));
typedef __bf16 bf16x4 __attribute__((ext_vector_type(4)));
typedef __bf16 bf16x8 __attribute__((ext_vector_type(8)));
typedef float f32x4 __attribute__((ext_vector_type(4)));
typedef unsigned u32x2 __attribute__((ext_vector_type(2)));

// XOR swizzle for [rows][32] bf16 LDS tiles (64B row stride).
__device__ __forceinline__ int swz(int row, int colb) {
    return (row * 64 + colb) ^ ((row & 7) << 4);
}

__device__ __forceinline__ unsigned packb(float a, float b) {
    bf16x2 t; t[0] = (bf16)a; t[1] = (bf16)b;
    return __builtin_bit_cast(unsigned, t);
}

// async global->LDS 16B copy (dest = wave-uniform base + lane*16)
__device__ __forceinline__ void gload16(void* lds, const void* g) {
    __builtin_amdgcn_global_load_lds(
        (const __attribute__((address_space(1))) void*)g,
        (__attribute__((address_space(3))) void*)lds, 16, 0, 0);
}

// ---------------- prep: q/k/v cvt + weight transpose + mask pack (one launch) --
__global__ __launch_bounds__(256) void prep_kernel(
    const float* __restrict__ q, const float* __restrict__ k, const float* __restrict__ v,
    bf16* __restrict__ oq, bf16* __restrict__ ok, bf16* __restrict__ ov,
    const float* __restrict__ w0, const float* __restrict__ w1,
    const float* __restrict__ w2, const float* __restrict__ w3,
    bf16* __restrict__ t0, bf16* __restrict__ t1,
    bf16* __restrict__ t2, bf16* __restrict__ t3,
    const int* __restrict__ mask, unsigned long long* __restrict__ mbits)
{
    int bid = blockIdx.x;
    int tid = threadIdx.x;
    __shared__ float tile[32][33];

    if (bid < 6144) {
        int z = bid >> 11;
        int bx = bid & 2047;
        const float* src = z == 0 ? q : z == 1 ? k : v;
        bf16* dst = z == 0 ? oq : z == 1 ? ok : ov;
        size_t i = ((size_t)bx * 256 + tid) * 8;
        f32x4 a = *(const f32x4*)(src + i);
        f32x4 b = *(const f32x4*)(src + i + 4);
        bf16x8 o;
#pragma unroll
        for (int j = 0; j < 4; ++j) { o[j] = (bf16)a[j]; o[4 + j] = (bf16)b[j]; }
        *(bf16x8*)(dst + i) = o;
    } else if (bid < 10240) {
        int wid = bid - 6144;
        int z = wid >> 10;
        int t = wid & 1023;
        const float* W = z == 0 ? w0 : z == 1 ? w1 : z == 2 ? w2 : w3;
        bf16* O = z == 0 ? t0 : z == 1 ? t1 : z == 2 ? t2 : t3;
        int c0 = (t & 31) * 32, r0 = (t >> 5) * 32;
        int tx = tid & 31, ty = tid >> 5; // (32,8)
#pragma unroll
        for (int i = 0; i < 4; ++i)
            tile[ty + i * 8][tx] = W[(size_t)(r0 + ty + i * 8) * 1024 + c0 + tx];
        __syncthreads();
#pragma unroll
        for (int i = 0; i < 4; ++i)
            O[(size_t)(c0 + ty + i * 8) * 1024 + r0 + tx] = (bf16)tile[tx][ty + i * 8];
    } else {
        int mb = bid - 10240;
        int lane = tid & 63;
        int wid = (mb * 256 + tid) >> 6;
        int nw = (256 * 256) >> 6;
        const int niter = (4 * 1024 * 1024) / 64;
        for (int i = wid; i < niter; i += nw) {
            int vv = mask[(size_t)i * 64 + lane];
            unsigned long long bb = __ballot(vv != 0);
            if (lane == 0) mbits[i] = bb;
        }
    }
}

// ---------------- projection GEMM (gload_lds staging) ----------------
// Grid (32 m-tiles, 8 n-tiles, 3): XCD = bid%8 = m-stripe -> each XCD keeps 4
// A-panels (1MB) L2-resident and fetches A once (was: n-stripe -> A fetched 8x).
// z==0/1: head-major Q/K. z==2: writes V^T (B,H,64,S) directly.
__global__ __launch_bounds__(256) void proj_gemm(
    const bf16* __restrict__ Aq, const bf16* __restrict__ Ak, const bf16* __restrict__ Av,
    const bf16* __restrict__ Wq, const bf16* __restrict__ Wk, const bf16* __restrict__ Wv,
    bf16* __restrict__ Oq, bf16* __restrict__ Ok, bf16* __restrict__ OvT)
{
    int z = blockIdx.z;
    const bf16* A = z == 0 ? Aq : z == 1 ? Ak : Av;
    const bf16* WT = z == 0 ? Wq : z == 1 ? Wk : Wv;

    __shared__ bf16 Al[128 * 32];
    __shared__ bf16 Bl[128 * 32];

    int tid = threadIdx.x;
    int w = tid >> 6, l = tid & 63;
    int l15 = l & 15, lg = l >> 4;
    int m0 = blockIdx.x * 128, n0 = blockIdx.y * 128;   // grid-transposed (T1)
    int wm = (w >> 1) * 64, wn = (w & 1) * 64;

    int rr0 = tid >> 2;
    int row0 = rr0 ^ ((rr0 >> 2) & 1);
    int cbe = (((tid & 3) * 16) ^ ((row0 & 3) << 4)) >> 1;
    char* aldst0 = (char*)Al + w * 1024;
    char* aldst1 = (char*)Al + 4096 + w * 1024;
    char* bldst0 = (char*)Bl + w * 1024;
    char* bldst1 = (char*)Bl + 4096 + w * 1024;
    const bf16* asrc0 = A + (size_t)(m0 + row0) * 1024 + cbe;
    const bf16* asrc1 = A + (size_t)(m0 + row0 + 64) * 1024 + cbe;
    const bf16* bsrc0 = WT + (size_t)(n0 + row0) * 1024 + cbe;
    const bf16* bsrc1 = WT + (size_t)(n0 + row0 + 64) * 1024 + cbe;

    const f32x4 fz = {0.f, 0.f, 0.f, 0.f};
    f32x4 acc[4][4];
#pragma unroll
    for (int i = 0; i < 4; ++i)
#pragma unroll
        for (int j = 0; j < 4; ++j) acc[i][j] = fz;

    for (int k0 = 0; k0 < 1024; k0 += 32) {
        gload16(aldst0, asrc0 + k0);
        gload16(aldst1, asrc1 + k0);
        gload16(bldst0, bsrc0 + k0);
        gload16(bldst1, bsrc1 + k0);
        __syncthreads();
        bf16x8 af[4], bv[4];
#pragma unroll
        for (int i = 0; i < 4; ++i)
            af[i] = *(const bf16x8*)((const char*)Al + swz(wm + i * 16 + l15, lg * 16));
#pragma unroll
        for (int j = 0; j < 4; ++j)
            bv[j] = *(const bf16x8*)((const char*)Bl + swz(wn + j * 16 + l15, lg * 16));
#pragma unroll
        for (int i = 0; i < 4; ++i)
#pragma unroll
            for (int j = 0; j < 4; ++j)
                acc[i][j] = __builtin_amdgcn_mfma_f32_16x16x32_bf16(af[i], bv[j], acc[i][j], 0, 0, 0);
        __syncthreads();
    }
    if (z < 2) {
        bf16* O = z == 0 ? Oq : Ok;
#pragma unroll
        for (int i = 0; i < 4; ++i)
#pragma unroll
            for (int j = 0; j < 4; ++j)
#pragma unroll
                for (int r = 0; r < 4; ++r) {
                    int m = m0 + wm + i * 16 + lg * 4 + r;
                    int n = n0 + wn + j * 16 + l15;
                    int bb = m >> 10, s = m & 1023, h = n >> 6, d = n & 63;
                    O[((size_t)(bb * 16 + h) * 1024 + s) * 64 + d] = (bf16)acc[i][j][r];
                }
    } else {
#pragma unroll
        for (int i = 0; i < 4; ++i)
#pragma unroll
            for (int j = 0; j < 4; ++j) {
                int m = m0 + wm + i * 16 + lg * 4;
                int n = n0 + wn + j * 16 + l15;
                int bb = m >> 10, s = m & 1023, h = n >> 6, d = n & 63;
                bf16x4 cv;
#pragma unroll
                for (int r = 0; r < 4; ++r) cv[r] = (bf16)acc[i][j][r];
                *(bf16x4*)(OvT + ((size_t)(bb * 16 + h) * 64 + d) * 1024 + s) = cv;
            }
    }
}

// ---------------- fused attention (R18: two-phase + XCD swizzle) --------------
__global__ __launch_bounds__(256, 4) void attn_fused(
    const bf16* __restrict__ Qh, const bf16* __restrict__ Kh,
    const bf16* __restrict__ VhT, const unsigned* __restrict__ mbits,
    bf16* __restrict__ ctx, float* __restrict__ attn_out)
{
    int bid = blockIdx.x;
    int wgid = (bid & 7) * 128 + (bid >> 3);   // bijective on [0,1024)
    int bh = wgid >> 4;
    int b = bh >> 4, h = bh & 15;
    int tid = threadIdx.x;
    int w = tid >> 6, l = tid & 63;
    int l15 = l & 15, lg = l >> 4;
    int q0 = (wgid & 15) * 64 + w * 16;

    const bf16* Qb = Qh + (size_t)bh * 65536;
    const bf16* Kb = Kh + (size_t)bh * 65536;
    const bf16* Vt = VhT + (size_t)bh * 65536;
    const unsigned* mbrow = mbits + ((size_t)b * 1024 + q0 + l15) * 32;

    __shared__ char lds[26624];
    __shared__ float sinv[64];
    // phase 1 layout
    char* const Kl = lds;                      // [64 keys][128B d] swz, 8KB
    char* const Vl = lds + 8192;               // [64 d][128B keys] swz, 8KB
    char* const St = lds + 16384 + w * 2048;   // wave-private [16 q][128B keys]
    // phase 2 layout (reuses lds)
    char* const K0 = lds;
    char* const K1 = lds + 8192;
    char* const S2 = lds + 16384 + w * 2560;   // 16 rows x 160B, wave-private

    const int skr = tid >> 2;            // row 0..63
    const int skb = (tid & 3) * 32;      // byte in 128B row
    const int sks = (skr & 7) << 4;
    const int rsw = (l15 & 7) << 4;
    const int ko0 = (lg * 16) ^ rsw;
    const int ko1 = (64 + lg * 16) ^ rsw;

    bf16x8 qf0 = *(const bf16x8*)(Qb + (size_t)(q0 + l15) * 64 + lg * 8);
    bf16x8 qf1 = *(const bf16x8*)(Qb + (size_t)(q0 + l15) * 64 + 32 + lg * 8);

    const f32x4 fz = {0.f, 0.f, 0.f, 0.f};

    // ================= phase 1 =================
    {   // prologue: stage chunk 0 (K and V)
        const bf16* src = Kb + (size_t)skr * 64 + (skb >> 1);
        bf16x8 a = *(const bf16x8*)src;
        bf16x8 b2 = *(const bf16x8*)(src + 8);
        const bf16* vsrc = Vt + (size_t)skr * 1024 + (skb >> 1);
        bf16x8 va = *(const bf16x8*)vsrc;
        bf16x8 vb = *(const bf16x8*)(vsrc + 8);
        *(bf16x8*)(Kl + skr * 128 + (skb ^ sks)) = a;
        *(bf16x8*)(Kl + skr * 128 + ((skb + 16) ^ sks)) = b2;
        *(bf16x8*)(Vl + skr * 128 + (skb ^ sks)) = va;
        *(bf16x8*)(Vl + skr * 128 + ((skb + 16) ^ sks)) = vb;
    }
    __syncthreads();

    f32x4 oacc[4];
#pragma unroll
    for (int d0 = 0; d0 < 4; ++d0) oacc[d0] = fz;
    float ps = 0.f;

    for (int c = 0; c < 16; ++c) {
        bf16x8 nk0, nk1, nv0, nv1;
        if (c < 15) {   // prefetch chunk c+1 into registers
            const bf16* src = Kb + (size_t)((c + 1) * 64 + skr) * 64 + (skb >> 1);
            nk0 = *(const bf16x8*)src;
            nk1 = *(const bf16x8*)(src + 8);
            const bf16* vsrc = Vt + (size_t)skr * 1024 + (c + 1) * 64 + (skb >> 1);
            nv0 = *(const bf16x8*)vsrc;
            nv1 = *(const bf16x8*)(vsrc + 8);
        }
        u32x2 mw = *(const u32x2*)(mbrow + c * 2);
        f32x4 st[4];
#pragma unroll
        for (int f = 0; f < 4; ++f) st[f] = fz;
#pragma unroll
        for (int f = 0; f < 4; ++f) {
            bf16x8 kf = *(const bf16x8*)(Kl + (f * 16 + l15) * 128 + ko0);
            st[f] = __builtin_amdgcn_mfma_f32_16x16x32_bf16(kf, qf0, st[f], 0, 0, 0);
        }
#pragma unroll
        for (int f = 0; f < 4; ++f) {
            bf16x8 kf = *(const bf16x8*)(Kl + (f * 16 + l15) * 128 + ko1);
            st[f] = __builtin_amdgcn_mfma_f32_16x16x32_bf16(kf, qf1, st[f], 0, 0, 0);
        }
        // masked exp; write P row-major into wave-private St
#pragma unroll
        for (int f = 0; f < 4; ++f) {
            unsigned wb = mw[f >> 1] >> (((f & 1) << 4) + (lg << 2));
            f32x4 o;
            o[0] = (wb & 1u)        ? __expf(st[f][0] * 0.125f) : 0.f;
            o[1] = ((wb >> 1) & 1u) ? __expf(st[f][1] * 0.125f) : 0.f;
            o[2] = ((wb >> 2) & 1u) ? __expf(st[f][2] * 0.125f) : 0.f;
            o[3] = ((wb >> 3) & 1u) ? __expf(st[f][3] * 0.125f) : 0.f;
            ps += (o[0] + o[1]) + (o[2] + o[3]);
            u32x2 pr; pr[0] = packb(o[0], o[1]); pr[1] = packb(o[2], o[3]);
            *(u32x2*)(St + l15 * 128 + ((f * 32 + lg * 8) ^ rsw)) = pr;
        }
        // PV: B-frag = contiguous read of St row q=l15
#pragma unroll
        for (int ks = 0; ks < 2; ++ks) {
            bf16x8 pf = *(const bf16x8*)(St + l15 * 128 + ((ks * 64 + lg * 16) ^ rsw));
#pragma unroll
            for (int d0 = 0; d0 < 4; ++d0) {
                bf16x8 vf = *(const bf16x8*)(Vl + (d0 * 16 + l15) * 128 + ((ks * 64 + lg * 16) ^ rsw));
                oacc[d0] = __builtin_amdgcn_mfma_f32_16x16x32_bf16(vf, pf, oacc[d0], 0, 0, 0);
            }
        }
        __syncthreads();
        if (c < 15) {
            *(bf16x8*)(Kl + skr * 128 + (skb ^ sks)) = nk0;
            *(bf16x8*)(Kl + skr * 128 + ((skb + 16) ^ sks)) = nk1;
            *(bf16x8*)(Vl + skr * 128 + (skb ^ sks)) = nv0;
            *(bf16x8*)(Vl + skr * 128 + ((skb + 16) ^ sks)) = nv1;
        }
        __syncthreads();
    }
    ps += __shfl_xor(ps, 16, 64);
    ps += __shfl_xor(ps, 32, 64);
    float inv = 1.f / ps;
    if (l < 16) sinv[w * 16 + l15] = inv;

    bf16* crow = ctx + ((size_t)(b * 1024 + q0 + l15)) * 1024 + h * 64;
#pragma unroll
    for (int d0 = 0; d0 < 4; ++d0) {
        bf16x4 cv;
#pragma unroll
        for (int r = 0; r < 4; ++r) cv[r] = (bf16)(oacc[d0][r] * inv);
        *(bf16x4*)(crow + d0 * 16 + lg * 4) = cv;
    }
    __syncthreads();   // sinv visible; all phase-1 LDS reads done

    // ================= phase 2 =================
    const int rq = l >> 3;               // 0..7
    const int rk = (l & 7) * 4;          // 0..28
    const float iv0 = sinv[w * 16 + rq];
    const float iv1 = sinv[w * 16 + 8 + rq];
    const unsigned* mb0 = mbits + ((size_t)b * 1024 + q0 + rq) * 32;
    const unsigned* mb1 = mbits + ((size_t)b * 1024 + q0 + 8 + rq) * 32;
    float* abase = attn_out + ((size_t)bh * 1024 + q0) * 1024;

    {   // stage chunk 0 K (L2-hot from phase 1)
        const bf16* src = Kb + (size_t)skr * 64 + (skb >> 1);
        bf16x8 a = *(const bf16x8*)src;
        bf16x8 bb2 = *(const bf16x8*)(src + 8);
        *(bf16x8*)(K0 + skr * 128 + (skb ^ sks)) = a;
        *(bf16x8*)(K0 + skr * 128 + ((skb + 16) ^ sks)) = bb2;
    }

    for (int c = 0; c < 16; ++c) {
        __syncthreads();
        bf16x8 nk0, nk1;
        if (c < 15) {
            const bf16* src = Kb + (size_t)((c + 1) * 64 + skr) * 64 + (skb >> 1);
            nk0 = *(const bf16x8*)src;
            nk1 = *(const bf16x8*)(src + 8);
        }
        u32x2 mw0 = *(const u32x2*)(mb0 + c * 2);
        u32x2 mw1 = *(const u32x2*)(mb1 + c * 2);
        const char* Kc = (c & 1) ? K1 : K0;
        f32x4 st[4];
#pragma unroll
        for (int f = 0; f < 4; ++f) st[f] = fz;
#pragma unroll
        for (int f = 0; f < 4; ++f) {
            bf16x8 kf = *(const bf16x8*)(Kc + (f * 16 + l15) * 128 + ko0);
            st[f] = __builtin_amdgcn_mfma_f32_16x16x32_bf16(kf, qf0, st[f], 0, 0, 0);
        }
#pragma unroll
        for (int f = 0; f < 4; ++f) {
            bf16x8 kf = *(const bf16x8*)(Kc + (f * 16 + l15) * 128 + ko1);
            st[f] = __builtin_amdgcn_mfma_f32_16x16x32_bf16(kf, qf1, st[f], 0, 0, 0);
        }
        const int qsw = (l15 & 7) << 3;
#pragma unroll
        for (int f = 0; f < 4; ++f) {
#pragma unroll
            for (int j = 0; j < 2; ++j) {
                unsigned val = packb(__expf(st[f][2 * j] * 0.125f),
                                     __expf(st[f][2 * j + 1] * 0.125f));
                int kbyte = f * 32 + lg * 8 + j * 4;
                *(unsigned*)(S2 + l15 * 160 + (kbyte ^ qsw)) = val;
            }
        }
#pragma unroll
        for (int ri = 0; ri < 4; ++ri) {
            int qq = rq + 8 * (ri & 1);
            int kk = rk + 32 * (ri >> 1);
            bf16x4 pv4 = *(const bf16x4*)(S2 + qq * 160 + ((kk * 2) ^ ((qq & 7) << 3)));
            unsigned wm = ((ri & 1) ? mw1[ri >> 1] : mw0[ri >> 1]) >> rk;
            float iv = (ri & 1) ? iv1 : iv0;
            f32x4 o;
            o[0] = (wm & 1u)        ? (float)pv4[0] * iv : 0.f;
            o[1] = ((wm >> 1) & 1u) ? (float)pv4[1] * iv : 0.f;
            o[2] = ((wm >> 2) & 1u) ? (float)pv4[2] * iv : 0.f;
            o[3] = ((wm >> 3) & 1u) ? (float)pv4[3] * iv : 0.f;
            // nontemporal: attn is write-once streaming output
            __builtin_nontemporal_store(o, (f32x4*)(abase + (size_t)qq * 1024 + c * 64 + kk));
        }
        if (c < 15) {
            char* kdst = ((c & 1) ? K0 : K1) + skr * 128;
            *(bf16x8*)(kdst + (skb ^ sks)) = nk0;
            *(bf16x8*)(kdst + ((skb + 16) ^ sks)) = nk1;
        }
    }
}

// ---------------- FC GEMM + residual -> preLN f32 ----------------
// Grid (32 m-tiles, 8 n-tiles): XCD = m-stripe -> ctx fetched once (was 8x).
__global__ __launch_bounds__(256) void fc_gemm(
    const bf16* __restrict__ ctx, const bf16* __restrict__ WT,
    const float* __restrict__ resid, float* __restrict__ preLN)
{
    __shared__ bf16 Al[128 * 32];
    __shared__ bf16 Bl[128 * 32];
    int tid = threadIdx.x;
    int w = tid >> 6, l = tid & 63;
    int l15 = l & 15, lg = l >> 4;
    int m0 = blockIdx.x * 128, n0 = blockIdx.y * 128;   // grid-transposed (T1)
    int wm = (w >> 1) * 64, wn = (w & 1) * 64;

    int rr0 = tid >> 2;
    int row0 = rr0 ^ ((rr0 >> 2) & 1);
    int cbe = (((tid & 3) * 16) ^ ((row0 & 3) << 4)) >> 1;
    char* aldst0 = (char*)Al + w * 1024;
    char* aldst1 = (char*)Al + 4096 + w * 1024;
    char* bldst0 = (char*)Bl + w * 1024;
    char* bldst1 = (char*)Bl + 4096 + w * 1024;
    const bf16* asrc0 = ctx + (size_t)(m0 + row0) * 1024 + cbe;
    const bf16* asrc1 = ctx + (size_t)(m0 + row0 + 64) * 1024 + cbe;
    const bf16* bsrc0 = WT + (size_t)(n0 + row0) * 1024 + cbe;
    const bf16* bsrc1 = WT + (size_t)(n0 + row0 + 64) * 1024 + cbe;

    const f32x4 fz = {0.f, 0.f, 0.f, 0.f};
    f32x4 acc[4][4];
#pragma unroll
    for (int i = 0; i < 4; ++i)
#pragma unroll
        for (int j = 0; j < 4; ++j) acc[i][j] = fz;

    for (int k0 = 0; k0 < 1024; k0 += 32) {
        gload16(aldst0, asrc0 + k0);
        gload16(aldst1, asrc1 + k0);
        gload16(bldst0, bsrc0 + k0);
        gload16(bldst1, bsrc1 + k0);
        __syncthreads();
        bf16x8 af[4], bv[4];
#pragma unroll
        for (int i = 0; i < 4; ++i)
            af[i] = *(const bf16x8*)((const char*)Al + swz(wm + i * 16 + l15, lg * 16));
#pragma unroll
        for (int j = 0; j < 4; ++j)
            bv[j] = *(const bf16x8*)((const char*)Bl + swz(wn + j * 16 + l15, lg * 16));
#pragma unroll
        for (int i = 0; i < 4; ++i)
#pragma unroll
            for (int j = 0; j < 4; ++j)
                acc[i][j] = __builtin_amdgcn_mfma_f32_16x16x32_bf16(af[i], bv[j], acc[i][j], 0, 0, 0);
        __syncthreads();
    }
#pragma unroll
    for (int i = 0; i < 4; ++i)
#pragma unroll
        for (int j = 0; j < 4; ++j)
#pragma unroll
            for (int r = 0; r < 4; ++r) {
                int m = m0 + wm + i * 16 + lg * 4 + r;
                int n = n0 + wn + j * 16 + l15;
                preLN[(size_t)m * 1024 + n] = acc[i][j][r] + resid[(size_t)m * 1024 + n];
            }
}

// ---------------- LayerNorm ----------------
__global__ __launch_bounds__(256) void ln_kernel(
    const float* __restrict__ x, const float* __restrict__ gamma,
    const float* __restrict__ beta, float* __restrict__ out)
{
    int row = blockIdx.x, t = threadIdx.x;
    const float* xr = x + (size_t)row * 1024;
    f32x4 v = *(const f32x4*)(xr + t * 4);
    float s = v[0] + v[1] + v[2] + v[3];
    float s2 = v[0] * v[0] + v[1] * v[1] + v[2] * v[2] + v[3] * v[3];
#pragma unroll
    for (int m = 1; m < 64; m <<= 1) {
        s += __shfl_xor(s, m, 64);
        s2 += __shfl_xor(s2, m, 64);
    }
    __shared__ float rs[4], rs2[4];
    if ((t & 63) == 0) { rs[t >> 6] = s; rs2[t >> 6] = s2; }
    __syncthreads();
    float S = rs[0] + rs[1] + rs[2] + rs[3];
    float S2 = rs2[0] + rs2[1] + rs2[2] + rs2[3];
    float mu = S * (1.f / 1024.f);
    float var = S2 * (1.f / 1024.f) - mu * mu;
    float rinv = rsqrtf(var + 1e-6f);
    f32x4 g = *(const f32x4*)(gamma + t * 4);
    f32x4 bb = *(const f32x4*)(beta + t * 4);
    f32x4 o;
#pragma unroll
    for (int j = 0; j < 4; ++j) o[j] = (v[j] - mu) * rinv * g[j] + bb[j];
    // out is a write-once streaming output (never re-read on device)
    __builtin_nontemporal_store(o, (f32x4*)(out + (size_t)row * 1024 + t * 4));
}

extern "C" void kernel_launch(void* const* d_in, const int* in_sizes, int n_in,
                              void* d_out, int out_size, void* d_ws, size_t ws_size,
                              hipStream_t stream) {
    const float* q     = (const float*)d_in[0];
    const float* k     = (const float*)d_in[1];
    const float* v     = (const float*)d_in[2];
    const int*   mask  = (const int*)d_in[3];
    const float* w_qs  = (const float*)d_in[4];
    const float* w_ks  = (const float*)d_in[5];
    const float* w_vs  = (const float*)d_in[6];
    const float* w_fc  = (const float*)d_in[7];
    const float* gamma = (const float*)d_in[8];
    const float* beta  = (const float*)d_in[9];

    float* out  = (float*)d_out;
    float* attn = out + (size_t)4 * 1024 * 1024; // second tuple output

    char* ws = (char*)d_ws;
    bf16* wqT   = (bf16*)(ws + (0ull  << 20));
    bf16* wkT   = (bf16*)(ws + (2ull  << 20));
    bf16* wvT   = (bf16*)(ws + (4ull  << 20));
    bf16* wfcT  = (bf16*)(ws + (6ull  << 20));
    bf16* Qh    = (bf16*)(ws + (8ull  << 20));
    bf16* Kh    = (bf16*)(ws + (16ull << 20));
    bf16* VhT   = (bf16*)(ws + (32ull << 20));
    bf16* ctx   = (bf16*)(ws + (40ull << 20));
    float* preLN = (float*)(ws + (48ull << 20));
    unsigned long long* mbits = (unsigned long long*)(ws + (25ull << 20)); // 512KB

    // bf16 copies of q/k/v live in the attn output region (dead until
    // attn_fused phase 2 overwrites every byte; proj reads them first).
    char* scratch = (char*)attn;
    bf16* qb = (bf16*)scratch;
    bf16* kb = qb + (size_t)4 * 1024 * 1024;
    bf16* vb = kb + (size_t)4 * 1024 * 1024;

    prep_kernel<<<10496, 256, 0, stream>>>(q, k, v, qb, kb, vb,
                                           w_qs, w_ks, w_vs, w_fc,
                                           wqT, wkT, wvT, wfcT,
                                           mask, mbits);
    proj_gemm<<<dim3(32, 8, 3), 256, 0, stream>>>(qb, kb, vb, wqT, wkT, wvT,
                                                  Qh, Kh, VhT);
    attn_fused<<<1024, 256, 0, stream>>>(Qh, Kh, VhT, (const unsigned*)mbits,
                                         ctx, attn);
    fc_gemm<<<dim3(32, 8), 256, 0, stream>>>(ctx, wfcT, q, preLN);
    ln_kernel<<<4096, 256, 0, stream>>>(preLN, gamma, beta, out);
}

// Round 21
// 173.435 us; speedup vs baseline: 1.1331x; 1.0209x over previous
//
#include <hip/hip_runtime.h>
#include <stdint.h>

typedef __bf16 bf16;
typedef __bf16 bf16x2 __attribute__((ext_vector_type(2)));
typedef __bf16 bf16x4 __attribute__((ext_vector_type(4)));
typedef __bf16 bf16x8 __attribute__((ext_vector_type(8)));
typedef float f32x4 __attribute__((ext_vector_type(4)));
typedef unsigned u32x2 __attribute__((ext_vector_type(2)));

// XOR swizzle for [rows][32] bf16 LDS tiles (64B row stride).
__device__ __forceinline__ int swz(int row, int colb) {
    return (row * 64 + colb) ^ ((row & 7) << 4);
}

__device__ __forceinline__ unsigned packb(float a, float b) {
    bf16x2 t; t[0] = (bf16)a; t[1] = (bf16)b;
    return __builtin_bit_cast(unsigned, t);
}

// async global->LDS 16B copy (dest = wave-uniform base + lane*16)
__device__ __forceinline__ void gload16(void* lds, const void* g) {
    __builtin_amdgcn_global_load_lds(
        (const __attribute__((address_space(1))) void*)g,
        (__attribute__((address_space(3))) void*)lds, 16, 0, 0);
}

// ---------------- prep: q/k/v cvt + weight transpose + mask pack (one launch) --
__global__ __launch_bounds__(256) void prep_kernel(
    const float* __restrict__ q, const float* __restrict__ k, const float* __restrict__ v,
    bf16* __restrict__ oq, bf16* __restrict__ ok, bf16* __restrict__ ov,
    const float* __restrict__ w0, const float* __restrict__ w1,
    const float* __restrict__ w2, const float* __restrict__ w3,
    bf16* __restrict__ t0, bf16* __restrict__ t1,
    bf16* __restrict__ t2, bf16* __restrict__ t3,
    const int* __restrict__ mask, unsigned long long* __restrict__ mbits)
{
    int bid = blockIdx.x;
    int tid = threadIdx.x;
    __shared__ float tile[32][33];

    if (bid < 6144) {
        int z = bid >> 11;
        int bx = bid & 2047;
        const float* src = z == 0 ? q : z == 1 ? k : v;
        bf16* dst = z == 0 ? oq : z == 1 ? ok : ov;
        size_t i = ((size_t)bx * 256 + tid) * 8;
        f32x4 a = *(const f32x4*)(src + i);
        f32x4 b = *(const f32x4*)(src + i + 4);
        bf16x8 o;
#pragma unroll
        for (int j = 0; j < 4; ++j) { o[j] = (bf16)a[j]; o[4 + j] = (bf16)b[j]; }
        *(bf16x8*)(dst + i) = o;
    } else if (bid < 10240) {
        int wid = bid - 6144;
        int z = wid >> 10;
        int t = wid & 1023;
        const float* W = z == 0 ? w0 : z == 1 ? w1 : z == 2 ? w2 : w3;
        bf16* O = z == 0 ? t0 : z == 1 ? t1 : z == 2 ? t2 : t3;
        int c0 = (t & 31) * 32, r0 = (t >> 5) * 32;
        int tx = tid & 31, ty = tid >> 5; // (32,8)
#pragma unroll
        for (int i = 0; i < 4; ++i)
            tile[ty + i * 8][tx] = W[(size_t)(r0 + ty + i * 8) * 1024 + c0 + tx];
        __syncthreads();
#pragma unroll
        for (int i = 0; i < 4; ++i)
            O[(size_t)(c0 + ty + i * 8) * 1024 + r0 + tx] = (bf16)tile[tx][ty + i * 8];
    } else {
        int mb = bid - 10240;
        int lane = tid & 63;
        int wid = (mb * 256 + tid) >> 6;
        int nw = (256 * 256) >> 6;
        const int niter = (4 * 1024 * 1024) / 64;
        for (int i = wid; i < niter; i += nw) {
            int vv = mask[(size_t)i * 64 + lane];
            unsigned long long bb = __ballot(vv != 0);
            if (lane == 0) mbits[i] = bb;
        }
    }
}

// ---------------- projection GEMM (gload_lds staging, m-stripe XCD grid) ------
__global__ __launch_bounds__(256) void proj_gemm(
    const bf16* __restrict__ Aq, const bf16* __restrict__ Ak, const bf16* __restrict__ Av,
    const bf16* __restrict__ Wq, const bf16* __restrict__ Wk, const bf16* __restrict__ Wv,
    bf16* __restrict__ Oq, bf16* __restrict__ Ok, bf16* __restrict__ OvT)
{
    int z = blockIdx.z;
    const bf16* A = z == 0 ? Aq : z == 1 ? Ak : Av;
    const bf16* WT = z == 0 ? Wq : z == 1 ? Wk : Wv;

    __shared__ bf16 Al[128 * 32];
    __shared__ bf16 Bl[128 * 32];

    int tid = threadIdx.x;
    int w = tid >> 6, l = tid & 63;
    int l15 = l & 15, lg = l >> 4;
    int m0 = blockIdx.x * 128, n0 = blockIdx.y * 128;   // grid-transposed (T1)
    int wm = (w >> 1) * 64, wn = (w & 1) * 64;

    int rr0 = tid >> 2;
    int row0 = rr0 ^ ((rr0 >> 2) & 1);
    int cbe = (((tid & 3) * 16) ^ ((row0 & 3) << 4)) >> 1;
    char* aldst0 = (char*)Al + w * 1024;
    char* aldst1 = (char*)Al + 4096 + w * 1024;
    char* bldst0 = (char*)Bl + w * 1024;
    char* bldst1 = (char*)Bl + 4096 + w * 1024;
    const bf16* asrc0 = A + (size_t)(m0 + row0) * 1024 + cbe;
    const bf16* asrc1 = A + (size_t)(m0 + row0 + 64) * 1024 + cbe;
    const bf16* bsrc0 = WT + (size_t)(n0 + row0) * 1024 + cbe;
    const bf16* bsrc1 = WT + (size_t)(n0 + row0 + 64) * 1024 + cbe;

    const f32x4 fz = {0.f, 0.f, 0.f, 0.f};
    f32x4 acc[4][4];
#pragma unroll
    for (int i = 0; i < 4; ++i)
#pragma unroll
        for (int j = 0; j < 4; ++j) acc[i][j] = fz;

    for (int k0 = 0; k0 < 1024; k0 += 32) {
        gload16(aldst0, asrc0 + k0);
        gload16(aldst1, asrc1 + k0);
        gload16(bldst0, bsrc0 + k0);
        gload16(bldst1, bsrc1 + k0);
        __syncthreads();
        bf16x8 af[4], bv[4];
#pragma unroll
        for (int i = 0; i < 4; ++i)
            af[i] = *(const bf16x8*)((const char*)Al + swz(wm + i * 16 + l15, lg * 16));
#pragma unroll
        for (int j = 0; j < 4; ++j)
            bv[j] = *(const bf16x8*)((const char*)Bl + swz(wn + j * 16 + l15, lg * 16));
#pragma unroll
        for (int i = 0; i < 4; ++i)
#pragma unroll
            for (int j = 0; j < 4; ++j)
                acc[i][j] = __builtin_amdgcn_mfma_f32_16x16x32_bf16(af[i], bv[j], acc[i][j], 0, 0, 0);
        __syncthreads();
    }
    if (z < 2) {
        bf16* O = z == 0 ? Oq : Ok;
#pragma unroll
        for (int i = 0; i < 4; ++i)
#pragma unroll
            for (int j = 0; j < 4; ++j)
#pragma unroll
                for (int r = 0; r < 4; ++r) {
                    int m = m0 + wm + i * 16 + lg * 4 + r;
                    int n = n0 + wn + j * 16 + l15;
                    int bb = m >> 10, s = m & 1023, h = n >> 6, d = n & 63;
                    O[((size_t)(bb * 16 + h) * 1024 + s) * 64 + d] = (bf16)acc[i][j][r];
                }
    } else {
#pragma unroll
        for (int i = 0; i < 4; ++i)
#pragma unroll
            for (int j = 0; j < 4; ++j) {
                int m = m0 + wm + i * 16 + lg * 4;
                int n = n0 + wn + j * 16 + l15;
                int bb = m >> 10, s = m & 1023, h = n >> 6, d = n & 63;
                bf16x4 cv;
#pragma unroll
                for (int r = 0; r < 4; ++r) cv[r] = (bf16)acc[i][j][r];
                *(bf16x4*)(OvT + ((size_t)(bb * 16 + h) * 64 + d) * 1024 + s) = cv;
            }
    }
}

// ---------------- fused attention (two-phase + XCD swizzle) -------------------
__global__ __launch_bounds__(256, 4) void attn_fused(
    const bf16* __restrict__ Qh, const bf16* __restrict__ Kh,
    const bf16* __restrict__ VhT, const unsigned* __restrict__ mbits,
    bf16* __restrict__ ctx, float* __restrict__ attn_out)
{
    int bid = blockIdx.x;
    int wgid = (bid & 7) * 128 + (bid >> 3);   // bijective on [0,1024)
    int bh = wgid >> 4;
    int b = bh >> 4, h = bh & 15;
    int tid = threadIdx.x;
    int w = tid >> 6, l = tid & 63;
    int l15 = l & 15, lg = l >> 4;
    int q0 = (wgid & 15) * 64 + w * 16;

    const bf16* Qb = Qh + (size_t)bh * 65536;
    const bf16* Kb = Kh + (size_t)bh * 65536;
    const bf16* Vt = VhT + (size_t)bh * 65536;
    const unsigned* mbrow = mbits + ((size_t)b * 1024 + q0 + l15) * 32;

    __shared__ char lds[26624];
    __shared__ float sinv[64];
    // phase 1 layout
    char* const Kl = lds;                      // [64 keys][128B d] swz, 8KB
    char* const Vl = lds + 8192;               // [64 d][128B keys] swz, 8KB
    char* const St = lds + 16384 + w * 2048;   // wave-private [16 q][128B keys]
    // phase 2 layout (reuses lds)
    char* const K0 = lds;
    char* const K1 = lds + 8192;
    char* const S2 = lds + 16384 + w * 2560;   // 16 rows x 160B, wave-private

    const int skr = tid >> 2;            // row 0..63
    const int skb = (tid & 3) * 32;      // byte in 128B row
    const int sks = (skr & 7) << 4;
    const int rsw = (l15 & 7) << 4;
    const int ko0 = (lg * 16) ^ rsw;
    const int ko1 = (64 + lg * 16) ^ rsw;

    bf16x8 qf0 = *(const bf16x8*)(Qb + (size_t)(q0 + l15) * 64 + lg * 8);
    bf16x8 qf1 = *(const bf16x8*)(Qb + (size_t)(q0 + l15) * 64 + 32 + lg * 8);

    const f32x4 fz = {0.f, 0.f, 0.f, 0.f};

    // ================= phase 1 =================
    {   // prologue: stage chunk 0 (K and V)
        const bf16* src = Kb + (size_t)skr * 64 + (skb >> 1);
        bf16x8 a = *(const bf16x8*)src;
        bf16x8 b2 = *(const bf16x8*)(src + 8);
        const bf16* vsrc = Vt + (size_t)skr * 1024 + (skb >> 1);
        bf16x8 va = *(const bf16x8*)vsrc;
        bf16x8 vb = *(const bf16x8*)(vsrc + 8);
        *(bf16x8*)(Kl + skr * 128 + (skb ^ sks)) = a;
        *(bf16x8*)(Kl + skr * 128 + ((skb + 16) ^ sks)) = b2;
        *(bf16x8*)(Vl + skr * 128 + (skb ^ sks)) = va;
        *(bf16x8*)(Vl + skr * 128 + ((skb + 16) ^ sks)) = vb;
    }
    __syncthreads();

    f32x4 oacc[4];
#pragma unroll
    for (int d0 = 0; d0 < 4; ++d0) oacc[d0] = fz;
    float ps = 0.f;

    for (int c = 0; c < 16; ++c) {
        bf16x8 nk0, nk1, nv0, nv1;
        if (c < 15) {   // prefetch chunk c+1 into registers
            const bf16* src = Kb + (size_t)((c + 1) * 64 + skr) * 64 + (skb >> 1);
            nk0 = *(const bf16x8*)src;
            nk1 = *(const bf16x8*)(src + 8);
            const bf16* vsrc = Vt + (size_t)skr * 1024 + (c + 1) * 64 + (skb >> 1);
            nv0 = *(const bf16x8*)vsrc;
            nv1 = *(const bf16x8*)(vsrc + 8);
        }
        u32x2 mw = *(const u32x2*)(mbrow + c * 2);
        f32x4 st[4];
#pragma unroll
        for (int f = 0; f < 4; ++f) st[f] = fz;
#pragma unroll
        for (int f = 0; f < 4; ++f) {
            bf16x8 kf = *(const bf16x8*)(Kl + (f * 16 + l15) * 128 + ko0);
            st[f] = __builtin_amdgcn_mfma_f32_16x16x32_bf16(kf, qf0, st[f], 0, 0, 0);
        }
#pragma unroll
        for (int f = 0; f < 4; ++f) {
            bf16x8 kf = *(const bf16x8*)(Kl + (f * 16 + l15) * 128 + ko1);
            st[f] = __builtin_amdgcn_mfma_f32_16x16x32_bf16(kf, qf1, st[f], 0, 0, 0);
        }
        // masked exp; write P row-major into wave-private St
#pragma unroll
        for (int f = 0; f < 4; ++f) {
            unsigned wb = mw[f >> 1] >> (((f & 1) << 4) + (lg << 2));
            f32x4 o;
            o[0] = (wb & 1u)        ? __expf(st[f][0] * 0.125f) : 0.f;
            o[1] = ((wb >> 1) & 1u) ? __expf(st[f][1] * 0.125f) : 0.f;
            o[2] = ((wb >> 2) & 1u) ? __expf(st[f][2] * 0.125f) : 0.f;
            o[3] = ((wb >> 3) & 1u) ? __expf(st[f][3] * 0.125f) : 0.f;
            ps += (o[0] + o[1]) + (o[2] + o[3]);
            u32x2 pr; pr[0] = packb(o[0], o[1]); pr[1] = packb(o[2], o[3]);
            *(u32x2*)(St + l15 * 128 + ((f * 32 + lg * 8) ^ rsw)) = pr;
        }
        // PV: B-frag = contiguous read of St row q=l15
#pragma unroll
        for (int ks = 0; ks < 2; ++ks) {
            bf16x8 pf = *(const bf16x8*)(St + l15 * 128 + ((ks * 64 + lg * 16) ^ rsw));
#pragma unroll
            for (int d0 = 0; d0 < 4; ++d0) {
                bf16x8 vf = *(const bf16x8*)(Vl + (d0 * 16 + l15) * 128 + ((ks * 64 + lg * 16) ^ rsw));
                oacc[d0] = __builtin_amdgcn_mfma_f32_16x16x32_bf16(vf, pf, oacc[d0], 0, 0, 0);
            }
        }
        __syncthreads();
        if (c < 15) {
            *(bf16x8*)(Kl + skr * 128 + (skb ^ sks)) = nk0;
            *(bf16x8*)(Kl + skr * 128 + ((skb + 16) ^ sks)) = nk1;
            *(bf16x8*)(Vl + skr * 128 + (skb ^ sks)) = nv0;
            *(bf16x8*)(Vl + skr * 128 + ((skb + 16) ^ sks)) = nv1;
        }
        __syncthreads();
    }
    ps += __shfl_xor(ps, 16, 64);
    ps += __shfl_xor(ps, 32, 64);
    float inv = 1.f / ps;
    if (l < 16) sinv[w * 16 + l15] = inv;

    bf16* crow = ctx + ((size_t)(b * 1024 + q0 + l15)) * 1024 + h * 64;
#pragma unroll
    for (int d0 = 0; d0 < 4; ++d0) {
        bf16x4 cv;
#pragma unroll
        for (int r = 0; r < 4; ++r) cv[r] = (bf16)(oacc[d0][r] * inv);
        *(bf16x4*)(crow + d0 * 16 + lg * 4) = cv;
    }
    __syncthreads();   // sinv visible; all phase-1 LDS reads done

    // ================= phase 2 =================
    const int rq = l >> 3;               // 0..7
    const int rk = (l & 7) * 4;          // 0..28
    const float iv0 = sinv[w * 16 + rq];
    const float iv1 = sinv[w * 16 + 8 + rq];
    const unsigned* mb0 = mbits + ((size_t)b * 1024 + q0 + rq) * 32;
    const unsigned* mb1 = mbits + ((size_t)b * 1024 + q0 + 8 + rq) * 32;
    float* abase = attn_out + ((size_t)bh * 1024 + q0) * 1024;

    {   // stage chunk 0 K (L2-hot from phase 1)
        const bf16* src = Kb + (size_t)skr * 64 + (skb >> 1);
        bf16x8 a = *(const bf16x8*)src;
        bf16x8 bb2 = *(const bf16x8*)(src + 8);
        *(bf16x8*)(K0 + skr * 128 + (skb ^ sks)) = a;
        *(bf16x8*)(K0 + skr * 128 + ((skb + 16) ^ sks)) = bb2;
    }

    for (int c = 0; c < 16; ++c) {
        __syncthreads();
        bf16x8 nk0, nk1;
        if (c < 15) {
            const bf16* src = Kb + (size_t)((c + 1) * 64 + skr) * 64 + (skb >> 1);
            nk0 = *(const bf16x8*)src;
            nk1 = *(const bf16x8*)(src + 8);
        }
        u32x2 mw0 = *(const u32x2*)(mb0 + c * 2);
        u32x2 mw1 = *(const u32x2*)(mb1 + c * 2);
        const char* Kc = (c & 1) ? K1 : K0;
        f32x4 st[4];
#pragma unroll
        for (int f = 0; f < 4; ++f) st[f] = fz;
#pragma unroll
        for (int f = 0; f < 4; ++f) {
            bf16x8 kf = *(const bf16x8*)(Kc + (f * 16 + l15) * 128 + ko0);
            st[f] = __builtin_amdgcn_mfma_f32_16x16x32_bf16(kf, qf0, st[f], 0, 0, 0);
        }
#pragma unroll
        for (int f = 0; f < 4; ++f) {
            bf16x8 kf = *(const bf16x8*)(Kc + (f * 16 + l15) * 128 + ko1);
            st[f] = __builtin_amdgcn_mfma_f32_16x16x32_bf16(kf, qf1, st[f], 0, 0, 0);
        }
        const int qsw = (l15 & 7) << 3;
#pragma unroll
        for (int f = 0; f < 4; ++f) {
#pragma unroll
            for (int j = 0; j < 2; ++j) {
                unsigned val = packb(__expf(st[f][2 * j] * 0.125f),
                                     __expf(st[f][2 * j + 1] * 0.125f));
                int kbyte = f * 32 + lg * 8 + j * 4;
                *(unsigned*)(S2 + l15 * 160 + (kbyte ^ qsw)) = val;
            }
        }
#pragma unroll
        for (int ri = 0; ri < 4; ++ri) {
            int qq = rq + 8 * (ri & 1);
            int kk = rk + 32 * (ri >> 1);
            bf16x4 pv4 = *(const bf16x4*)(S2 + qq * 160 + ((kk * 2) ^ ((qq & 7) << 3)));
            unsigned wm = ((ri & 1) ? mw1[ri >> 1] : mw0[ri >> 1]) >> rk;
            float iv = (ri & 1) ? iv1 : iv0;
            f32x4 o;
            o[0] = (wm & 1u)        ? (float)pv4[0] * iv : 0.f;
            o[1] = ((wm >> 1) & 1u) ? (float)pv4[1] * iv : 0.f;
            o[2] = ((wm >> 2) & 1u) ? (float)pv4[2] * iv : 0.f;
            o[3] = ((wm >> 3) & 1u) ? (float)pv4[3] * iv : 0.f;
            // nontemporal: attn is write-once streaming output
            __builtin_nontemporal_store(o, (f32x4*)(abase + (size_t)qq * 1024 + c * 64 + kk));
        }
        if (c < 15) {
            char* kdst = ((c & 1) ? K0 : K1) + skr * 128;
            *(bf16x8*)(kdst + (skb ^ sks)) = nk0;
            *(bf16x8*)(kdst + ((skb + 16) ^ sks)) = nk1;
        }
    }
}

// ---------------- FC GEMM + residual -> preLN bf16 ----------------
// Grid (32 m-tiles, 8 n-tiles): XCD = m-stripe -> ctx fetched once.
// preLN stored as bf16 (write-once intermediate; LN tolerates the quantization).
__global__ __launch_bounds__(256) void fc_gemm(
    const bf16* __restrict__ ctx, const bf16* __restrict__ WT,
    const float* __restrict__ resid, bf16* __restrict__ preLN)
{
    __shared__ bf16 Al[128 * 32];
    __shared__ bf16 Bl[128 * 32];
    int tid = threadIdx.x;
    int w = tid >> 6, l = tid & 63;
    int l15 = l & 15, lg = l >> 4;
    int m0 = blockIdx.x * 128, n0 = blockIdx.y * 128;   // grid-transposed (T1)
    int wm = (w >> 1) * 64, wn = (w & 1) * 64;

    int rr0 = tid >> 2;
    int row0 = rr0 ^ ((rr0 >> 2) & 1);
    int cbe = (((tid & 3) * 16) ^ ((row0 & 3) << 4)) >> 1;
    char* aldst0 = (char*)Al + w * 1024;
    char* aldst1 = (char*)Al + 4096 + w * 1024;
    char* bldst0 = (char*)Bl + w * 1024;
    char* bldst1 = (char*)Bl + 4096 + w * 1024;
    const bf16* asrc0 = ctx + (size_t)(m0 + row0) * 1024 + cbe;
    const bf16* asrc1 = ctx + (size_t)(m0 + row0 + 64) * 1024 + cbe;
    const bf16* bsrc0 = WT + (size_t)(n0 + row0) * 1024 + cbe;
    const bf16* bsrc1 = WT + (size_t)(n0 + row0 + 64) * 1024 + cbe;

    const f32x4 fz = {0.f, 0.f, 0.f, 0.f};
    f32x4 acc[4][4];
#pragma unroll
    for (int i = 0; i < 4; ++i)
#pragma unroll
        for (int j = 0; j < 4; ++j) acc[i][j] = fz;

    for (int k0 = 0; k0 < 1024; k0 += 32) {
        gload16(aldst0, asrc0 + k0);
        gload16(aldst1, asrc1 + k0);
        gload16(bldst0, bsrc0 + k0);
        gload16(bldst1, bsrc1 + k0);
        __syncthreads();
        bf16x8 af[4], bv[4];
#pragma unroll
        for (int i = 0; i < 4; ++i)
            af[i] = *(const bf16x8*)((const char*)Al + swz(wm + i * 16 + l15, lg * 16));
#pragma unroll
        for (int j = 0; j < 4; ++j)
            bv[j] = *(const bf16x8*)((const char*)Bl + swz(wn + j * 16 + l15, lg * 16));
#pragma unroll
        for (int i = 0; i < 4; ++i)
#pragma unroll
            for (int j = 0; j < 4; ++j)
                acc[i][j] = __builtin_amdgcn_mfma_f32_16x16x32_bf16(af[i], bv[j], acc[i][j], 0, 0, 0);
        __syncthreads();
    }
#pragma unroll
    for (int i = 0; i < 4; ++i)
#pragma unroll
        for (int j = 0; j < 4; ++j)
#pragma unroll
            for (int r = 0; r < 4; ++r) {
                int m = m0 + wm + i * 16 + lg * 4 + r;
                int n = n0 + wn + j * 16 + l15;
                preLN[(size_t)m * 1024 + n] =
                    (bf16)(acc[i][j][r] + resid[(size_t)m * 1024 + n]);
            }
}

// ---------------- LayerNorm (bf16 input, nt loads) ----------------
__global__ __launch_bounds__(256) void ln_kernel(
    const bf16* __restrict__ x, const float* __restrict__ gamma,
    const float* __restrict__ beta, float* __restrict__ out)
{
    int row = blockIdx.x, t = threadIdx.x;
    const bf16* xr = x + (size_t)row * 1024 + t * 4;
    bf16x4 xv = __builtin_nontemporal_load((const bf16x4*)xr);
    f32x4 v;
#pragma unroll
    for (int j = 0; j < 4; ++j) v[j] = (float)xv[j];
    float s = v[0] + v[1] + v[2] + v[3];
    float s2 = v[0] * v[0] + v[1] * v[1] + v[2] * v[2] + v[3] * v[3];
#pragma unroll
    for (int m = 1; m < 64; m <<= 1) {
        s += __shfl_xor(s, m, 64);
        s2 += __shfl_xor(s2, m, 64);
    }
    __shared__ float rs[4], rs2[4];
    if ((t & 63) == 0) { rs[t >> 6] = s; rs2[t >> 6] = s2; }
    __syncthreads();
    float S = rs[0] + rs[1] + rs[2] + rs[3];
    float S2 = rs2[0] + rs2[1] + rs2[2] + rs2[3];
    float mu = S * (1.f / 1024.f);
    float var = S2 * (1.f / 1024.f) - mu * mu;
    float rinv = rsqrtf(var + 1e-6f);
    f32x4 g = *(const f32x4*)(gamma + t * 4);
    f32x4 bb = *(const f32x4*)(beta + t * 4);
    f32x4 o;
#pragma unroll
    for (int j = 0; j < 4; ++j) o[j] = (v[j] - mu) * rinv * g[j] + bb[j];
    // out is a write-once streaming output (never re-read on device)
    __builtin_nontemporal_store(o, (f32x4*)(out + (size_t)row * 1024 + t * 4));
}

extern "C" void kernel_launch(void* const* d_in, const int* in_sizes, int n_in,
                              void* d_out, int out_size, void* d_ws, size_t ws_size,
                              hipStream_t stream) {
    const float* q     = (const float*)d_in[0];
    const float* k     = (const float*)d_in[1];
    const float* v     = (const float*)d_in[2];
    const int*   mask  = (const int*)d_in[3];
    const float* w_qs  = (const float*)d_in[4];
    const float* w_ks  = (const float*)d_in[5];
    const float* w_vs  = (const float*)d_in[6];
    const float* w_fc  = (const float*)d_in[7];
    const float* gamma = (const float*)d_in[8];
    const float* beta  = (const float*)d_in[9];

    float* out  = (float*)d_out;
    float* attn = out + (size_t)4 * 1024 * 1024; // second tuple output

    char* ws = (char*)d_ws;
    bf16* wqT   = (bf16*)(ws + (0ull  << 20));
    bf16* wkT   = (bf16*)(ws + (2ull  << 20));
    bf16* wvT   = (bf16*)(ws + (4ull  << 20));
    bf16* wfcT  = (bf16*)(ws + (6ull  << 20));
    bf16* Qh    = (bf16*)(ws + (8ull  << 20));
    bf16* Kh    = (bf16*)(ws + (16ull << 20));
    bf16* VhT   = (bf16*)(ws + (32ull << 20));
    bf16* ctx   = (bf16*)(ws + (40ull << 20));
    bf16* preLN = (bf16*)(ws + (48ull << 20));
    unsigned long long* mbits = (unsigned long long*)(ws + (25ull << 20)); // 512KB

    // bf16 copies of q/k/v live in the attn output region (dead until
    // attn_fused phase 2 overwrites every byte; proj reads them first).
    char* scratch = (char*)attn;
    bf16* qb = (bf16*)scratch;
    bf16* kb = qb + (size_t)4 * 1024 * 1024;
    bf16* vb = kb + (size_t)4 * 1024 * 1024;

    prep_kernel<<<10496, 256, 0, stream>>>(q, k, v, qb, kb, vb,
                                           w_qs, w_ks, w_vs, w_fc,
                                           wqT, wkT, wvT, wfcT,
                                           mask, mbits);
    proj_gemm<<<dim3(32, 8, 3), 256, 0, stream>>>(qb, kb, vb, wqT, wkT, wvT,
                                                  Qh, Kh, VhT);
    attn_fused<<<1024, 256, 0, stream>>>(Qh, Kh, VhT, (const unsigned*)mbits,
                                         ctx, attn);
    fc_gemm<<<dim3(32, 8), 256, 0, stream>>>(ctx, wfcT, q, preLN);
    ln_kernel<<<4096, 256, 0, stream>>>(preLN, gamma, beta, out);
}